// Round 7
// baseline (665.885 us; speedup 1.0000x reference)
//
#include <hip/hip_runtime.h>

#define BN_EPS 1e-5f

constexpr int BSH = 9;          // 512 nodes per bucket
constexpr int MAXB = 200;       // max buckets supported (N <= 102400)
constexpr int CAP = 12288;      // temp capacity (pairs) per bucket
constexpr int BINCAP = 32;      // LDS bin capacity per bucket (pairs)
constexpr int FLUSH = 16;       // flush granularity (pairs)
constexpr int SBLK = 256;       // bn_stats grid

// ---------------- init ----------------

__global__ void initk(int* __restrict__ gcur, float* __restrict__ bn, int NB) {
  int t = blockIdx.x * blockDim.x + threadIdx.x;
  if (t < NB) gcur[t] = t * CAP;
  if (t < 512) bn[t] = 0.f;
}

// goffs from sorted batch: goffs[g] = first node index of graph g; goffs[B] = N
__global__ void bound_kernel(const int* __restrict__ batch, int* __restrict__ goffs, int N, int B) {
  int i = blockIdx.x * blockDim.x + threadIdx.x;
  if (i < N) {
    int b = batch[i];
    int p = (i == 0) ? -1 : batch[i - 1];
    for (int g = p + 1; g <= b; ++g) goffs[g] = i;
    if (i == N - 1) {
      for (int g = b + 1; g <= B; ++g) goffs[g] = N;
    }
  }
}

// ---------------- bucketed CSR build ----------------

__global__ __launch_bounds__(256) void passA(const int* __restrict__ dst, const int* __restrict__ src,
                                             int* __restrict__ gcur, unsigned long long* __restrict__ temp,
                                             int E, int NB) {
  __shared__ unsigned long long bins[MAXB * BINCAP];
  __shared__ int bcnt[MAXB];
  int tid = threadIdx.x;
  for (int b = tid; b < NB; b += 256) bcnt[b] = 0;
  __syncthreads();
  int chunk = (E + gridDim.x - 1) / gridDim.x;
  int e0 = blockIdx.x * chunk;
  int e1 = min(e0 + chunk, E);
  for (int base = e0; base < e1; base += 1024) {
#pragma unroll
    for (int j = 0; j < 4; ++j) {
      int e = base + tid * 4 + j;
      if (e < e1) {
        int d = dst[e];
        int s = src[e];
        int b = d >> BSH;
        unsigned long long pk = ((unsigned long long)(unsigned)s << 32) | (unsigned)d;
        int slot = atomicAdd(&bcnt[b], 1);
        if (slot < BINCAP) {
          bins[b * BINCAP + slot] = pk;
        } else {  // rare spill: direct global (correctness fallback)
          int p = atomicAdd(&gcur[b], 1);
          temp[p] = pk;
        }
      }
    }
    __syncthreads();
    if (tid < NB) {
      int c = min(bcnt[tid], BINCAP);
      while (c >= FLUSH) {
        int p = atomicAdd(&gcur[tid], FLUSH);
        for (int j = 0; j < FLUSH; ++j) temp[p + j] = bins[tid * BINCAP + j];
        c -= FLUSH;
        for (int j = 0; j < c; ++j) bins[tid * BINCAP + j] = bins[tid * BINCAP + FLUSH + j];
      }
      bcnt[tid] = c;
    }
    __syncthreads();
  }
  if (tid < NB) {
    int c = min(bcnt[tid], BINCAP);
    if (c > 0) {
      int p = atomicAdd(&gcur[tid], c);
      for (int j = 0; j < c; ++j) temp[p + j] = bins[tid * BINCAP + j];
    }
  }
}

__global__ __launch_bounds__(512) void passB1(const unsigned long long* __restrict__ temp,
                                              const int* __restrict__ gcur,
                                              int* __restrict__ deg, float* __restrict__ dinv, int N) {
  __shared__ int h[512];
  int b = blockIdx.x, t = threadIdx.x;
  h[t] = 0;
  __syncthreads();
  int cnt = min(gcur[b] - b * CAP, CAP);
  const unsigned long long* tp = temp + (size_t)b * CAP;
  for (int i = t; i < cnt; i += 512) {
    int d = (int)(tp[i] & 0xffffffffu);
    atomicAdd(&h[d & 511], 1);
  }
  __syncthreads();
  int node = (b << BSH) + t;
  if (node < N) {
    deg[node] = h[t];
    dinv[node] = rsqrtf((float)h[t] + 1.f);
  }
}

__global__ __launch_bounds__(512) void passB2(const unsigned long long* __restrict__ temp,
                                              const int* __restrict__ gcur,
                                              const int* __restrict__ offs,
                                              int* __restrict__ csr, int N) {
  __shared__ int lofs[512];
  __shared__ int lcnt[512];
  int b = blockIdx.x, t = threadIdx.x;
  int node = (b << BSH) + t;
  lofs[t] = offs[min(node, N)];
  lcnt[t] = 0;
  __syncthreads();
  int cnt = min(gcur[b] - b * CAP, CAP);
  const unsigned long long* tp = temp + (size_t)b * CAP;
  for (int i = t; i < cnt; i += 512) {
    unsigned long long pk = tp[i];
    int d = (int)(pk & 0xffffffffu) & 511;
    int s = (int)(pk >> 32);
    int pos = lofs[d] + atomicAdd(&lcnt[d], 1);
    csr[pos] = s;
  }
}

// ---------------- 3-phase exclusive scan for CSR offsets ----------------

__global__ __launch_bounds__(1024) void scan_p1(const int* __restrict__ cnt,
                                                int* __restrict__ offs,
                                                int* __restrict__ bsum, int n) {
  __shared__ int sh[1024];
  int t = threadIdx.x;
  int i = blockIdx.x * 1024 + t;
  int v = (i < n) ? cnt[i] : 0;
  sh[t] = v;
  __syncthreads();
  for (int d = 1; d < 1024; d <<= 1) {
    int x = (t >= d) ? sh[t - d] : 0;
    __syncthreads();
    sh[t] += x;
    __syncthreads();
  }
  if (i < n) offs[i] = sh[t] - v;
  if (t == 1023) bsum[blockIdx.x] = sh[t];
}

__global__ void scan_p2(int* __restrict__ bsum, int nb) {
  __shared__ int sh[128];
  int t = threadIdx.x;
  int v = (t < nb) ? bsum[t] : 0;
  sh[t] = v;
  __syncthreads();
  for (int d = 1; d < 128; d <<= 1) {
    int x = (t >= d) ? sh[t - d] : 0;
    __syncthreads();
    sh[t] += x;
    __syncthreads();
  }
  if (t < nb) bsum[t] = sh[t] - v;
}

__global__ __launch_bounds__(1024) void scan_p3(int* __restrict__ offs,
                                                const int* __restrict__ bsum, int n, int E) {
  int i = blockIdx.x * 1024 + threadIdx.x;
  if (i < n) offs[i] += bsum[blockIdx.x];
  if (i == 0) offs[n] = E;
}

// ---------------- pre-layer transforms ----------------

__global__ void pre1_kernel(const float* __restrict__ x, const float* __restrict__ dinv,
                            float* __restrict__ u1, int N) {
  int stride = gridDim.x * blockDim.x;
  for (int i = blockIdx.x * blockDim.x + threadIdx.x; i < N * 32; i += stride) {
    int row = i >> 5, f = i & 31;
    u1[i] = (f < 20) ? x[row * 20 + f] * dinv[row] : 0.f;
  }
}

__global__ void u_kernel(const float* __restrict__ z, const float* __restrict__ ta,
                         const float* __restrict__ tc, const float* __restrict__ dinv,
                         float* __restrict__ u, int N) {
  int stride = gridDim.x * blockDim.x;
  for (int i = blockIdx.x * blockDim.x + threadIdx.x; i < N * 16; i += stride) {
    int row = i >> 4, f = (i & 15) * 4;
    float4 v = ((const float4*)z)[i];
    float dv = dinv[row];
    float4 o;
    o.x = fmaxf(v.x * ta[f] + tc[f], 0.f) * dv;
    o.y = fmaxf(v.y * ta[f + 1] + tc[f + 1], 0.f) * dv;
    o.z = fmaxf(v.z * ta[f + 2] + tc[f + 2], 0.f) * dv;
    o.w = fmaxf(v.w * ta[f + 3] + tc[f + 3], 0.f) * dv;
    ((float4*)u)[i] = o;
  }
}

// ---------------- aggregation ----------------

__global__ __launch_bounds__(256) void agg32_kernel(const float* __restrict__ u,
                                                    const int* __restrict__ offs,
                                                    const int* __restrict__ csr,
                                                    float* __restrict__ out, int n) {
  int lane = threadIdx.x & 63;
  int wid = threadIdx.x >> 6;
  int half = lane >> 5, f = lane & 31;
  int gw = blockIdx.x * 4 + wid, nw = gridDim.x * 4;
  for (int i = gw; i < n; i += nw) {
    float acc = half ? 0.f : u[(size_t)i * 32 + f];
    int st = offs[i], en = offs[i + 1];
    for (int base = st; base < en; base += 64) {
      int idx = base + lane;
      int v = (idx < en) ? csr[idx] : 0;
      int cnt = min(64, en - base);
      int j = 0;
      for (; j + 3 < cnt; j += 4) {
        int s0 = __shfl(v, j + half);
        int s1 = __shfl(v, j + 2 + half);
        acc += u[(size_t)s0 * 32 + f] + u[(size_t)s1 * 32 + f];
      }
      for (; j < cnt; ++j) {
        int s = __shfl(v, j);
        if (!half) acc += u[(size_t)s * 32 + f];
      }
    }
    acc += __shfl_xor(acc, 32);
    if (!half) out[(size_t)i * 32 + f] = acc;
  }
}

template <bool SCALE>
__global__ __launch_bounds__(256) void agg64_kernel(const float* __restrict__ u,
                                                    const int* __restrict__ offs,
                                                    const int* __restrict__ csr,
                                                    const float* __restrict__ dinv,
                                                    float* __restrict__ out, int n) {
  int lane = threadIdx.x & 63;
  int wid = threadIdx.x >> 6;
  int gw = blockIdx.x * 4 + wid, nw = gridDim.x * 4;
  for (int i = gw; i < n; i += nw) {
    float acc = u[(size_t)i * 64 + lane];
    int st = offs[i], en = offs[i + 1];
    for (int base = st; base < en; base += 64) {
      int idx = base + lane;
      int v = (idx < en) ? csr[idx] : 0;
      int cnt = min(64, en - base);
      int j = 0;
      for (; j + 3 < cnt; j += 4) {
        int s0 = __shfl(v, j), s1 = __shfl(v, j + 1);
        int s2 = __shfl(v, j + 2), s3 = __shfl(v, j + 3);
        acc += u[(size_t)s0 * 64 + lane] + u[(size_t)s1 * 64 + lane] +
               u[(size_t)s2 * 64 + lane] + u[(size_t)s3 * 64 + lane];
      }
      for (; j < cnt; ++j) {
        int s = __shfl(v, j);
        acc += u[(size_t)s * 64 + lane];
      }
    }
    if (SCALE) acc *= dinv[i];
    out[(size_t)i * 64 + lane] = acc;
  }
}

// ---------------- GEMM: z = dinv*(a@W) + bias (no stats; 128 rows/block, 2 rows/thread) ----

template <int K, int AS>
__global__ __launch_bounds__(256) void gemm_agg(const float* __restrict__ A, const float* __restrict__ W,
                                                const float* __restrict__ bias, const float* __restrict__ dinv,
                                                float* __restrict__ z, int n) {
  __shared__ float Ws[K * 64];
  __shared__ float As[128 * (K + 1)];
  int tid = threadIdx.x;
  int row0 = blockIdx.x * 128;
  for (int i = tid; i < K * 64; i += 256) Ws[i] = W[i];
  for (int i = tid; i < 128 * K; i += 256) {
    int r = i / K, k = i - r * K;
    int gr = row0 + r;
    As[r * (K + 1) + k] = (gr < n) ? A[(size_t)gr * AS + k] : 0.f;
  }
  __syncthreads();
  int rg = tid >> 2;   // 0..63 -> rows 2rg, 2rg+1
  int fs = tid & 3;    // feature slice fs*16..fs*16+15
  float acc0[16], acc1[16];
#pragma unroll
  for (int j = 0; j < 16; ++j) { acc0[j] = 0.f; acc1[j] = 0.f; }
  const float* a0 = &As[(2 * rg) * (K + 1)];
  const float* a1 = &As[(2 * rg + 1) * (K + 1)];
  const float* wb = &Ws[fs * 16];
  for (int k = 0; k < K; ++k) {
    float x0 = a0[k], x1 = a1[k];
#pragma unroll
    for (int j = 0; j < 16; ++j) {
      float w = wb[k * 64 + j];
      acc0[j] += x0 * w;
      acc1[j] += x1 * w;
    }
  }
  int r0 = row0 + 2 * rg;
  if (r0 < n) {
    float dv = dinv[r0];
    float4* zp = (float4*)&z[(size_t)r0 * 64 + fs * 16];
#pragma unroll
    for (int j = 0; j < 16; j += 4)
      zp[j >> 2] = make_float4(acc0[j] * dv + bias[fs * 16 + j], acc0[j + 1] * dv + bias[fs * 16 + j + 1],
                               acc0[j + 2] * dv + bias[fs * 16 + j + 2], acc0[j + 3] * dv + bias[fs * 16 + j + 3]);
  }
  int r1 = r0 + 1;
  if (r1 < n) {
    float dv = dinv[r1];
    float4* zp = (float4*)&z[(size_t)r1 * 64 + fs * 16];
#pragma unroll
    for (int j = 0; j < 16; j += 4)
      zp[j >> 2] = make_float4(acc1[j] * dv + bias[fs * 16 + j], acc1[j + 1] * dv + bias[fs * 16 + j + 1],
                               acc1[j + 2] * dv + bias[fs * 16 + j + 2], acc1[j + 3] * dv + bias[fs * 16 + j + 3]);
  }
}

// ---------------- BN stats: per-block partials, zero atomics ----------------

__global__ __launch_bounds__(256) void bn_stats(const float* __restrict__ z,
                                                float* __restrict__ partial, int N) {
  int lane = threadIdx.x & 63, wid = threadIdx.x >> 6;
  int gw = blockIdx.x * 4 + wid, nw = gridDim.x * 4;
  float s = 0.f, q = 0.f;
  for (int r = gw; r < N; r += nw) {
    float v = z[(size_t)r * 64 + lane];
    s += v;
    q += v * v;
  }
  __shared__ float sh[2][4][64];
  sh[0][wid][lane] = s;
  sh[1][wid][lane] = q;
  __syncthreads();
  if (wid == 0) {
    float ts = sh[0][0][lane] + sh[0][1][lane] + sh[0][2][lane] + sh[0][3][lane];
    float tq = sh[1][0][lane] + sh[1][1][lane] + sh[1][2][lane] + sh[1][3][lane];
    partial[blockIdx.x * 128 + lane] = ts;
    partial[blockIdx.x * 128 + 64 + lane] = tq;
  }
}

__global__ void bn_final_kernel(const float* __restrict__ partial, int nb,
                                const float* __restrict__ g, const float* __restrict__ bt,
                                float* __restrict__ a, float* __restrict__ c, float n) {
  int f = threadIdx.x;
  float s = 0.f, q = 0.f;
  for (int i = 0; i < nb; ++i) {
    s += partial[i * 128 + f];
    q += partial[i * 128 + 64 + f];
  }
  float mu = s / n;
  float var = fmaxf(q / n - mu * mu, 0.f);
  float rstd = rsqrtf(var + BN_EPS);
  float av = g[f] * rstd;
  a[f] = av;
  c[f] = bt[f] - mu * av;
}

// ---------------- pool ----------------

__global__ __launch_bounds__(64) void pool_kernel(const float* __restrict__ v3,
                                                  const int* __restrict__ goffs,
                                                  float* __restrict__ ep, int B) {
  int b = blockIdx.x, t = threadIdx.x;
  int st = goffs[b], en = goffs[b + 1];
  float s = 0.f;
  int r = st;
  for (; r + 1 < en; r += 2) s += v3[(size_t)r * 64 + t] + v3[(size_t)(r + 1) * 64 + t];
  if (r < en) s += v3[(size_t)r * 64 + t];
  int c = en - st;
  ep[(size_t)b * 64 + t] = s / (float)max(c, 1);
}

// ---------------- heads ----------------

__global__ __launch_bounds__(256) void heads_kernel(
    const float* __restrict__ ep, const int* __restrict__ goffs,
    const float* __restrict__ W3, const float* __restrict__ b3,
    const float* __restrict__ Wo1, const float* __restrict__ bo1,
    const float* __restrict__ Wo2, const float* __restrict__ bo2,
    const float* __restrict__ Wp1, const float* __restrict__ bp1,
    const float* __restrict__ Wp2, const float* __restrict__ bp2,
    const float* __restrict__ Wp3, const float* __restrict__ bp3,
    const float* __restrict__ Wd1, const float* __restrict__ bd1,
    const float* __restrict__ Wd2, const float* __restrict__ bd2,
    float* __restrict__ out_op, float* __restrict__ out_p, float* __restrict__ out_d,
    float* __restrict__ enc_out, int B) {
  __shared__ float epl[16 * 64];
  __shared__ float es[16 * 128];
  __shared__ float t1[16 * 64];
  __shared__ float t2[16 * 64];
  int tid = threadIdx.x;
  int g0 = blockIdx.x * 16;
  for (int i = tid; i < 16 * 64; i += 256) epl[i] = ep[(size_t)g0 * 64 + i];
  __syncthreads();
  for (int o = tid; o < 16 * 128; o += 256) {
    int r = o >> 7, c = o & 127;
    float a = b3[c];
    for (int k = 0; k < 64; ++k) a += epl[r * 64 + k] * W3[k * 128 + c];
    if (goffs[g0 + r + 1] - goffs[g0 + r] == 0) a = 0.f;
    es[o] = a;
    enc_out[(size_t)(g0 + r) * 128 + c] = a;
  }
  __syncthreads();
  for (int o = tid; o < 16 * 64; o += 256) {
    int r = o >> 6, c = o & 63;
    float a = bo1[c];
    for (int k = 0; k < 128; k++) a += es[r * 128 + k] * Wo1[k * 64 + c];
    t1[o] = fmaxf(a, 0.f);
  }
  __syncthreads();
  for (int o = tid; o < 16 * 13; o += 256) {
    int r = o / 13, c = o - r * 13;
    float a = bo2[c];
    for (int k = 0; k < 64; k++) a += t1[r * 64 + k] * Wo2[k * 13 + c];
    out_op[(size_t)(g0 + r) * 13 + c] = a;
  }
  __syncthreads();
  for (int o = tid; o < 16 * 64; o += 256) {
    int r = o >> 6, c = o & 63;
    float a = bp1[c];
    for (int k = 0; k < 128; k++) a += es[r * 128 + k] * Wp1[k * 64 + c];
    t1[o] = fmaxf(a, 0.f);
  }
  __syncthreads();
  for (int o = tid; o < 16 * 64; o += 256) {
    int r = o >> 6, c = o & 63;
    float a = bp2[c];
    for (int k = 0; k < 64; k++) a += t1[r * 64 + k] * Wp2[k * 64 + c];
    t2[o] = fmaxf(a, 0.f);
  }
  __syncthreads();
  for (int o = tid; o < 16; o += 256) {
    float a = bp3[0];
    for (int k = 0; k < 64; k++) a += t2[o * 64 + k] * Wp3[k];
    out_p[g0 + o] = a;
  }
  __syncthreads();
  for (int o = tid; o < 16 * 64; o += 256) {
    int r = o >> 6, c = o & 63;
    float a = bd1[c];
    for (int k = 0; k < 128; k++) a += es[r * 128 + k] * Wd1[k * 64 + c];
    t1[o] = fmaxf(a, 0.f);
  }
  __syncthreads();
  for (int o = tid; o < 16 * 2; o += 256) {
    int r = o >> 1, c = o & 1;
    float a = bd2[c];
    for (int k = 0; k < 64; k++) a += t1[r * 64 + k] * Wd2[k * 2 + c];
    out_d[(size_t)(g0 + r) * 2 + c] = a;
  }
}

// ---------------- launch ----------------

extern "C" void kernel_launch(void* const* d_in, const int* in_sizes, int n_in,
                              void* d_out, int out_size, void* d_ws, size_t ws_size,
                              hipStream_t stream) {
  const float* x   = (const float*)d_in[0];
  const int*   ei  = (const int*)d_in[1];
  const int*   bat = (const int*)d_in[2];
  const float* W1 = (const float*)d_in[3];  const float* b1  = (const float*)d_in[4];
  const float* g1 = (const float*)d_in[5];  const float* bt1 = (const float*)d_in[6];
  const float* W2 = (const float*)d_in[7];  const float* b2  = (const float*)d_in[8];
  const float* g2 = (const float*)d_in[9];  const float* bt2 = (const float*)d_in[10];
  const float* W3 = (const float*)d_in[11]; const float* b3  = (const float*)d_in[12];
  const float* Wo1 = (const float*)d_in[13]; const float* bo1 = (const float*)d_in[14];
  const float* Wo2 = (const float*)d_in[15]; const float* bo2 = (const float*)d_in[16];
  const float* Wp1 = (const float*)d_in[17]; const float* bp1 = (const float*)d_in[18];
  const float* Wp2 = (const float*)d_in[19]; const float* bp2 = (const float*)d_in[20];
  const float* Wp3 = (const float*)d_in[21]; const float* bp3 = (const float*)d_in[22];
  const float* Wd1 = (const float*)d_in[23]; const float* bd1 = (const float*)d_in[24];
  const float* Wd2 = (const float*)d_in[25]; const float* bd2 = (const float*)d_in[26];

  int N = in_sizes[0] / 20;
  int E = in_sizes[1] / 2;
  int B = out_size / 144;  // 13 + 1 + 2 + 128
  const int* esrc = ei;
  const int* edst = ei + E;
  int NB = (N + (1 << BSH) - 1) >> BSH;

  char* ws = (char*)d_ws;
  size_t off = 0;
  auto alloc = [&](size_t bytes) -> char* {
    char* p = ws + off;
    off = (off + bytes + 255) & ~(size_t)255;
    return p;
  };
  int*   gcur  = (int*)alloc((size_t)NB * 4);
  int*   deg   = (int*)alloc((size_t)N * 4);
  float* dinv  = (float*)alloc((size_t)N * 4);
  int*   offs  = (int*)alloc(((size_t)N + 1) * 4);
  int*   bsum  = (int*)alloc(128 * 4);
  int*   goffs = (int*)alloc(((size_t)B + 1) * 4);
  float* bn    = (float*)alloc(512 * 4);
  float* partial = (float*)alloc((size_t)SBLK * 128 * 4);
  unsigned long long* temp = (unsigned long long*)alloc((size_t)NB * CAP * 8);
  int*   csr   = (int*)alloc((size_t)E * 4);
  float* bufA  = (float*)alloc((size_t)N * 64 * 4);
  float* bufB  = (float*)alloc((size_t)N * 64 * 4);
  float* ep    = (float*)alloc((size_t)B * 64 * 4);

  float* ta1 = bn + 256, *tc1 = bn + 320;
  float* ta2 = bn + 384, *tc2 = bn + 448;

  float* out_op = (float*)d_out;
  float* out_p  = out_op + (size_t)B * 13;
  float* out_d  = out_p + B;
  float* enc    = out_d + (size_t)B * 2;

  hipLaunchKernelGGL(initk, dim3(2), dim3(256), 0, stream, gcur, bn, NB);
  hipLaunchKernelGGL(bound_kernel, dim3((N + 255) / 256), dim3(256), 0, stream, bat, goffs, N, B);
  hipLaunchKernelGGL(passA, dim3(256), dim3(256), 0, stream, edst, esrc, gcur, temp, E, NB);
  hipLaunchKernelGGL(passB1, dim3(NB), dim3(512), 0, stream, temp, gcur, deg, dinv, N);
  int nb1 = (N + 1023) / 1024;
  hipLaunchKernelGGL(scan_p1, dim3(nb1), dim3(1024), 0, stream, deg, offs, bsum, N);
  hipLaunchKernelGGL(scan_p2, dim3(1), dim3(128), 0, stream, bsum, nb1);
  hipLaunchKernelGGL(scan_p3, dim3(nb1), dim3(1024), 0, stream, offs, bsum, N, E);
  hipLaunchKernelGGL(passB2, dim3(NB), dim3(512), 0, stream, temp, gcur, offs, csr, N);

  int gblocks = (N + 127) / 128;
  // layer 1
  hipLaunchKernelGGL(pre1_kernel, dim3(2048), dim3(256), 0, stream, x, dinv, bufA, N);
  hipLaunchKernelGGL(agg32_kernel, dim3(2048), dim3(256), 0, stream, bufA, offs, csr, bufB, N);
  hipLaunchKernelGGL((gemm_agg<20, 32>), dim3(gblocks), dim3(256), 0, stream,
                     bufB, W1, b1, dinv, bufA, N);
  hipLaunchKernelGGL(bn_stats, dim3(SBLK), dim3(256), 0, stream, bufA, partial, N);
  hipLaunchKernelGGL(bn_final_kernel, dim3(1), dim3(64), 0, stream,
                     partial, SBLK, g1, bt1, ta1, tc1, (float)N);
  // layer 2
  hipLaunchKernelGGL(u_kernel, dim3(2048), dim3(256), 0, stream, bufA, ta1, tc1, dinv, bufB, N);
  hipLaunchKernelGGL((agg64_kernel<false>), dim3(2048), dim3(256), 0, stream,
                     bufB, offs, csr, dinv, bufA, N);
  hipLaunchKernelGGL((gemm_agg<64, 64>), dim3(gblocks), dim3(256), 0, stream,
                     bufA, W2, b2, dinv, bufB, N);
  hipLaunchKernelGGL(bn_stats, dim3(SBLK), dim3(256), 0, stream, bufB, partial, N);
  hipLaunchKernelGGL(bn_final_kernel, dim3(1), dim3(64), 0, stream,
                     partial, SBLK, g2, bt2, ta2, tc2, (float)N);
  // layer 3 (pre-GEMM space)
  hipLaunchKernelGGL(u_kernel, dim3(2048), dim3(256), 0, stream, bufB, ta2, tc2, dinv, bufA, N);
  hipLaunchKernelGGL((agg64_kernel<true>), dim3(2048), dim3(256), 0, stream,
                     bufA, offs, csr, dinv, bufB, N);
  hipLaunchKernelGGL(pool_kernel, dim3(B), dim3(64), 0, stream, bufB, goffs, ep, B);
  hipLaunchKernelGGL(heads_kernel, dim3(B / 16), dim3(256), 0, stream, ep, goffs, W3, b3,
                     Wo1, bo1, Wo2, bo2, Wp1, bp1, Wp2, bp2, Wp3, bp3, Wd1, bd1, Wd2, bd2,
                     out_op, out_p, out_d, enc, B);
}

// Round 8
// 532.757 us; speedup vs baseline: 1.2499x; 1.2499x over previous
//
#include <hip/hip_runtime.h>

#define BN_EPS 1e-5f

constexpr int BSH = 9;          // 512 nodes per bucket
constexpr int MAXB = 200;       // max buckets supported (N <= 102400)
constexpr int CAP = 12288;      // temp capacity (pairs) per bucket
constexpr int BINCAP = 32;      // LDS bin capacity per bucket (pairs)
constexpr int FLUSH = 16;       // flush granularity (pairs)
constexpr int SBLK = 256;       // bn_stats grid (must stay 256: bn_final assumes it)

// ---------------- init ----------------

__global__ void initk(int* __restrict__ gcur, float* __restrict__ bn, int NB) {
  int t = blockIdx.x * blockDim.x + threadIdx.x;
  if (t < NB) gcur[t] = t * CAP;
  if (t < 512) bn[t] = 0.f;
}

// goffs from sorted batch: goffs[g] = first node index of graph g; goffs[B] = N
__global__ void bound_kernel(const int* __restrict__ batch, int* __restrict__ goffs, int N, int B) {
  int i = blockIdx.x * blockDim.x + threadIdx.x;
  if (i < N) {
    int b = batch[i];
    int p = (i == 0) ? -1 : batch[i - 1];
    for (int g = p + 1; g <= b; ++g) goffs[g] = i;
    if (i == N - 1) {
      for (int g = b + 1; g <= B; ++g) goffs[g] = N;
    }
  }
}

// ---------------- bucketed CSR build ----------------

__global__ __launch_bounds__(256) void passA(const int* __restrict__ dst, const int* __restrict__ src,
                                             int* __restrict__ gcur, unsigned long long* __restrict__ temp,
                                             int E, int NB) {
  __shared__ unsigned long long bins[MAXB * BINCAP];
  __shared__ int bcnt[MAXB];
  int tid = threadIdx.x;
  for (int b = tid; b < NB; b += 256) bcnt[b] = 0;
  __syncthreads();
  int chunk = (E + gridDim.x - 1) / gridDim.x;
  int e0 = blockIdx.x * chunk;
  int e1 = min(e0 + chunk, E);
  for (int base = e0; base < e1; base += 1024) {
#pragma unroll
    for (int j = 0; j < 4; ++j) {
      int e = base + tid * 4 + j;
      if (e < e1) {
        int d = dst[e];
        int s = src[e];
        int b = d >> BSH;
        unsigned long long pk = ((unsigned long long)(unsigned)s << 32) | (unsigned)d;
        int slot = atomicAdd(&bcnt[b], 1);
        if (slot < BINCAP) {
          bins[b * BINCAP + slot] = pk;
        } else {  // rare spill: direct global (correctness fallback)
          int p = atomicAdd(&gcur[b], 1);
          temp[p] = pk;
        }
      }
    }
    __syncthreads();
    if (tid < NB) {
      int c = min(bcnt[tid], BINCAP);
      while (c >= FLUSH) {
        int p = atomicAdd(&gcur[tid], FLUSH);
        for (int j = 0; j < FLUSH; ++j) temp[p + j] = bins[tid * BINCAP + j];
        c -= FLUSH;
        for (int j = 0; j < c; ++j) bins[tid * BINCAP + j] = bins[tid * BINCAP + FLUSH + j];
      }
      bcnt[tid] = c;
    }
    __syncthreads();
  }
  if (tid < NB) {
    int c = min(bcnt[tid], BINCAP);
    if (c > 0) {
      int p = atomicAdd(&gcur[tid], c);
      for (int j = 0; j < c; ++j) temp[p + j] = bins[tid * BINCAP + j];
    }
  }
}

__global__ __launch_bounds__(512) void passB1(const unsigned long long* __restrict__ temp,
                                              const int* __restrict__ gcur,
                                              int* __restrict__ deg, float* __restrict__ dinv, int N) {
  __shared__ int h[512];
  int b = blockIdx.x, t = threadIdx.x;
  h[t] = 0;
  __syncthreads();
  int cnt = min(gcur[b] - b * CAP, CAP);
  const unsigned long long* tp = temp + (size_t)b * CAP;
  for (int i = t; i < cnt; i += 512) {
    int d = (int)(tp[i] & 0xffffffffu);
    atomicAdd(&h[d & 511], 1);
  }
  __syncthreads();
  int node = (b << BSH) + t;
  if (node < N) {
    deg[node] = h[t];
    dinv[node] = rsqrtf((float)h[t] + 1.f);
  }
}

__global__ __launch_bounds__(512) void passB2(const unsigned long long* __restrict__ temp,
                                              const int* __restrict__ gcur,
                                              const int* __restrict__ offs,
                                              int* __restrict__ csr, int N) {
  __shared__ int lofs[512];
  __shared__ int lcnt[512];
  int b = blockIdx.x, t = threadIdx.x;
  int node = (b << BSH) + t;
  lofs[t] = offs[min(node, N)];
  lcnt[t] = 0;
  __syncthreads();
  int cnt = min(gcur[b] - b * CAP, CAP);
  const unsigned long long* tp = temp + (size_t)b * CAP;
  for (int i = t; i < cnt; i += 512) {
    unsigned long long pk = tp[i];
    int d = (int)(pk & 0xffffffffu) & 511;
    int s = (int)(pk >> 32);
    int pos = lofs[d] + atomicAdd(&lcnt[d], 1);
    csr[pos] = s;
  }
}

// ---------------- 3-phase exclusive scan for CSR offsets ----------------

__global__ __launch_bounds__(1024) void scan_p1(const int* __restrict__ cnt,
                                                int* __restrict__ offs,
                                                int* __restrict__ bsum, int n) {
  __shared__ int sh[1024];
  int t = threadIdx.x;
  int i = blockIdx.x * 1024 + t;
  int v = (i < n) ? cnt[i] : 0;
  sh[t] = v;
  __syncthreads();
  for (int d = 1; d < 1024; d <<= 1) {
    int x = (t >= d) ? sh[t - d] : 0;
    __syncthreads();
    sh[t] += x;
    __syncthreads();
  }
  if (i < n) offs[i] = sh[t] - v;
  if (t == 1023) bsum[blockIdx.x] = sh[t];
}

__global__ void scan_p2(int* __restrict__ bsum, int nb) {
  __shared__ int sh[128];
  int t = threadIdx.x;
  int v = (t < nb) ? bsum[t] : 0;
  sh[t] = v;
  __syncthreads();
  for (int d = 1; d < 128; d <<= 1) {
    int x = (t >= d) ? sh[t - d] : 0;
    __syncthreads();
    sh[t] += x;
    __syncthreads();
  }
  if (t < nb) bsum[t] = sh[t] - v;
}

__global__ __launch_bounds__(1024) void scan_p3(int* __restrict__ offs,
                                                const int* __restrict__ bsum, int n, int E) {
  int i = blockIdx.x * 1024 + threadIdx.x;
  if (i < n) offs[i] += bsum[blockIdx.x];
  if (i == 0) offs[n] = E;
}

// ---------------- aggregation (transform fused into gather) ----------------

// layer 1: gathers x directly (20-wide rows), scales by dinv[src], pads to 32
__global__ __launch_bounds__(256) void agg32x_kernel(const float* __restrict__ x,
                                                     const int* __restrict__ offs,
                                                     const int* __restrict__ csr,
                                                     const float* __restrict__ dinv,
                                                     float* __restrict__ out, int n) {
  int lane = threadIdx.x & 63;
  int wid = threadIdx.x >> 6;
  int half = lane >> 5, f = lane & 31;
  bool act = f < 20;
  int gw = blockIdx.x * 4 + wid, nw = gridDim.x * 4;
  for (int i = gw; i < n; i += nw) {
    float acc = 0.f;
    if (!half && act) acc = x[(size_t)i * 20 + f] * dinv[i];
    int st = offs[i], en = offs[i + 1];
    for (int base = st; base < en; base += 64) {
      int idx = base + lane;
      int v = (idx < en) ? csr[idx] : 0;
      int cnt = min(64, en - base);
      int j = 0;
      for (; j + 3 < cnt; j += 4) {
        int s0 = __shfl(v, j + half);
        int s1 = __shfl(v, j + 2 + half);
        if (act) acc += x[(size_t)s0 * 20 + f] * dinv[s0] + x[(size_t)s1 * 20 + f] * dinv[s1];
      }
      for (; j < cnt; ++j) {
        int s = __shfl(v, j);
        if (!half && act) acc += x[(size_t)s * 20 + f] * dinv[s];
      }
    }
    acc += __shfl_xor(acc, 32);
    if (!half) out[(size_t)i * 32 + f] = acc;
  }
}

// layers 2/3: gathers z rows, applying T(v,row) = relu(v*ta+tc)*dinv[row] on the fly.
// SCALE: multiply the total by dinv[i] (layer-3 pre-pool form)
template <bool SCALE>
__global__ __launch_bounds__(256) void agg64t_kernel(const float* __restrict__ z,
                                                     const float* __restrict__ tav,
                                                     const float* __restrict__ tcv,
                                                     const int* __restrict__ offs,
                                                     const int* __restrict__ csr,
                                                     const float* __restrict__ dinv,
                                                     float* __restrict__ out, int n) {
  int lane = threadIdx.x & 63;
  int wid = threadIdx.x >> 6;
  float ta = tav[lane], tc = tcv[lane];
  int gw = blockIdx.x * 4 + wid, nw = gridDim.x * 4;
  for (int i = gw; i < n; i += nw) {
    float di = dinv[i];
    float acc = fmaxf(z[(size_t)i * 64 + lane] * ta + tc, 0.f) * di;
    int st = offs[i], en = offs[i + 1];
    for (int base = st; base < en; base += 64) {
      int idx = base + lane;
      int v = (idx < en) ? csr[idx] : 0;
      int cnt = min(64, en - base);
      int j = 0;
      for (; j + 3 < cnt; j += 4) {
        int s0 = __shfl(v, j), s1 = __shfl(v, j + 1);
        int s2 = __shfl(v, j + 2), s3 = __shfl(v, j + 3);
        float d0 = dinv[s0], d1 = dinv[s1], d2 = dinv[s2], d3 = dinv[s3];
        acc += fmaxf(z[(size_t)s0 * 64 + lane] * ta + tc, 0.f) * d0 +
               fmaxf(z[(size_t)s1 * 64 + lane] * ta + tc, 0.f) * d1 +
               fmaxf(z[(size_t)s2 * 64 + lane] * ta + tc, 0.f) * d2 +
               fmaxf(z[(size_t)s3 * 64 + lane] * ta + tc, 0.f) * d3;
      }
      for (; j < cnt; ++j) {
        int s = __shfl(v, j);
        acc += fmaxf(z[(size_t)s * 64 + lane] * ta + tc, 0.f) * dinv[s];
      }
    }
    if (SCALE) acc *= di;
    out[(size_t)i * 64 + lane] = acc;
  }
}

// ---------------- GEMM: z = dinv*(a@W) + bias (128 rows/block, 2 rows/thread) ----

template <int K, int AS>
__global__ __launch_bounds__(256) void gemm_agg(const float* __restrict__ A, const float* __restrict__ W,
                                                const float* __restrict__ bias, const float* __restrict__ dinv,
                                                float* __restrict__ z, int n) {
  __shared__ float Ws[K * 64];
  __shared__ float As[128 * (K + 1)];
  int tid = threadIdx.x;
  int row0 = blockIdx.x * 128;
  for (int i = tid; i < K * 64; i += 256) Ws[i] = W[i];
  for (int i = tid; i < 128 * K; i += 256) {
    int r = i / K, k = i - r * K;
    int gr = row0 + r;
    As[r * (K + 1) + k] = (gr < n) ? A[(size_t)gr * AS + k] : 0.f;
  }
  __syncthreads();
  int rg = tid >> 2;   // 0..63 -> rows 2rg, 2rg+1
  int fs = tid & 3;    // feature slice fs*16..fs*16+15
  float acc0[16], acc1[16];
#pragma unroll
  for (int j = 0; j < 16; ++j) { acc0[j] = 0.f; acc1[j] = 0.f; }
  const float* a0 = &As[(2 * rg) * (K + 1)];
  const float* a1 = &As[(2 * rg + 1) * (K + 1)];
  const float* wb = &Ws[fs * 16];
  for (int k = 0; k < K; ++k) {
    float x0 = a0[k], x1 = a1[k];
#pragma unroll
    for (int j = 0; j < 16; ++j) {
      float w = wb[k * 64 + j];
      acc0[j] += x0 * w;
      acc1[j] += x1 * w;
    }
  }
  int r0 = row0 + 2 * rg;
  if (r0 < n) {
    float dv = dinv[r0];
    float4* zp = (float4*)&z[(size_t)r0 * 64 + fs * 16];
#pragma unroll
    for (int j = 0; j < 16; j += 4)
      zp[j >> 2] = make_float4(acc0[j] * dv + bias[fs * 16 + j], acc0[j + 1] * dv + bias[fs * 16 + j + 1],
                               acc0[j + 2] * dv + bias[fs * 16 + j + 2], acc0[j + 3] * dv + bias[fs * 16 + j + 3]);
  }
  int r1 = r0 + 1;
  if (r1 < n) {
    float dv = dinv[r1];
    float4* zp = (float4*)&z[(size_t)r1 * 64 + fs * 16];
#pragma unroll
    for (int j = 0; j < 16; j += 4)
      zp[j >> 2] = make_float4(acc1[j] * dv + bias[fs * 16 + j], acc1[j + 1] * dv + bias[fs * 16 + j + 1],
                               acc1[j + 2] * dv + bias[fs * 16 + j + 2], acc1[j + 3] * dv + bias[fs * 16 + j + 3]);
  }
}

// ---------------- BN stats: per-block partials, zero atomics ----------------

__global__ __launch_bounds__(256) void bn_stats(const float* __restrict__ z,
                                                float* __restrict__ partial, int N) {
  int lane = threadIdx.x & 63, wid = threadIdx.x >> 6;
  int gw = blockIdx.x * 4 + wid, nw = gridDim.x * 4;
  float s = 0.f, q = 0.f;
  for (int r = gw; r < N; r += nw) {
    float v = z[(size_t)r * 64 + lane];
    s += v;
    q += v * v;
  }
  __shared__ float sh[2][4][64];
  sh[0][wid][lane] = s;
  sh[1][wid][lane] = q;
  __syncthreads();
  if (wid == 0) {
    float ts = sh[0][0][lane] + sh[0][1][lane] + sh[0][2][lane] + sh[0][3][lane];
    float tq = sh[1][0][lane] + sh[1][1][lane] + sh[1][2][lane] + sh[1][3][lane];
    partial[blockIdx.x * 128 + lane] = ts;
    partial[blockIdx.x * 128 + 64 + lane] = tq;
  }
}

// parallel finalize: 1024 threads = 16 groups x 64 lanes; each group sums 16 of
// the 256 partials, LDS tree-reduce across groups (fixes the 65us 1-wave serial loop)
__global__ __launch_bounds__(1024) void bn_final_kernel(const float* __restrict__ partial,
                                                        const float* __restrict__ g,
                                                        const float* __restrict__ bt,
                                                        float* __restrict__ a, float* __restrict__ c,
                                                        float n) {
  __shared__ float sh[16][128];
  int t = threadIdx.x;
  int grp = t >> 6, lane = t & 63;
  float s = 0.f, q = 0.f;
#pragma unroll
  for (int k = 0; k < 16; ++k) {
    int i = grp * 16 + k;
    s += partial[i * 128 + lane];
    q += partial[i * 128 + 64 + lane];
  }
  sh[grp][lane] = s;
  sh[grp][64 + lane] = q;
  __syncthreads();
  for (int str = 8; str >= 1; str >>= 1) {
    if (grp < str) {
      sh[grp][lane] += sh[grp + str][lane];
      sh[grp][64 + lane] += sh[grp + str][64 + lane];
    }
    __syncthreads();
  }
  if (grp == 0) {
    float mu = sh[0][lane] / n;
    float var = fmaxf(sh[0][64 + lane] / n - mu * mu, 0.f);
    float rstd = rsqrtf(var + BN_EPS);
    float av = g[lane] * rstd;
    a[lane] = av;
    c[lane] = bt[lane] - mu * av;
  }
}

// ---------------- pool ----------------

__global__ __launch_bounds__(64) void pool_kernel(const float* __restrict__ v3,
                                                  const int* __restrict__ goffs,
                                                  float* __restrict__ ep, int B) {
  int b = blockIdx.x, t = threadIdx.x;
  int st = goffs[b], en = goffs[b + 1];
  float s = 0.f;
  int r = st;
  for (; r + 1 < en; r += 2) s += v3[(size_t)r * 64 + t] + v3[(size_t)(r + 1) * 64 + t];
  if (r < en) s += v3[(size_t)r * 64 + t];
  int c = en - st;
  ep[(size_t)b * 64 + t] = s / (float)max(c, 1);
}

// ---------------- heads ----------------

__global__ __launch_bounds__(256) void heads_kernel(
    const float* __restrict__ ep, const int* __restrict__ goffs,
    const float* __restrict__ W3, const float* __restrict__ b3,
    const float* __restrict__ Wo1, const float* __restrict__ bo1,
    const float* __restrict__ Wo2, const float* __restrict__ bo2,
    const float* __restrict__ Wp1, const float* __restrict__ bp1,
    const float* __restrict__ Wp2, const float* __restrict__ bp2,
    const float* __restrict__ Wp3, const float* __restrict__ bp3,
    const float* __restrict__ Wd1, const float* __restrict__ bd1,
    const float* __restrict__ Wd2, const float* __restrict__ bd2,
    float* __restrict__ out_op, float* __restrict__ out_p, float* __restrict__ out_d,
    float* __restrict__ enc_out, int B) {
  __shared__ float epl[16 * 64];
  __shared__ float es[16 * 128];
  __shared__ float t1[16 * 64];
  __shared__ float t2[16 * 64];
  int tid = threadIdx.x;
  int g0 = blockIdx.x * 16;
  for (int i = tid; i < 16 * 64; i += 256) epl[i] = ep[(size_t)g0 * 64 + i];
  __syncthreads();
  for (int o = tid; o < 16 * 128; o += 256) {
    int r = o >> 7, c = o & 127;
    float a = b3[c];
    for (int k = 0; k < 64; ++k) a += epl[r * 64 + k] * W3[k * 128 + c];
    if (goffs[g0 + r + 1] - goffs[g0 + r] == 0) a = 0.f;
    es[o] = a;
    enc_out[(size_t)(g0 + r) * 128 + c] = a;
  }
  __syncthreads();
  for (int o = tid; o < 16 * 64; o += 256) {
    int r = o >> 6, c = o & 63;
    float a = bo1[c];
    for (int k = 0; k < 128; k++) a += es[r * 128 + k] * Wo1[k * 64 + c];
    t1[o] = fmaxf(a, 0.f);
  }
  __syncthreads();
  for (int o = tid; o < 16 * 13; o += 256) {
    int r = o / 13, c = o - r * 13;
    float a = bo2[c];
    for (int k = 0; k < 64; k++) a += t1[r * 64 + k] * Wo2[k * 13 + c];
    out_op[(size_t)(g0 + r) * 13 + c] = a;
  }
  __syncthreads();
  for (int o = tid; o < 16 * 64; o += 256) {
    int r = o >> 6, c = o & 63;
    float a = bp1[c];
    for (int k = 0; k < 128; k++) a += es[r * 128 + k] * Wp1[k * 64 + c];
    t1[o] = fmaxf(a, 0.f);
  }
  __syncthreads();
  for (int o = tid; o < 16 * 64; o += 256) {
    int r = o >> 6, c = o & 63;
    float a = bp2[c];
    for (int k = 0; k < 64; k++) a += t1[r * 64 + k] * Wp2[k * 64 + c];
    t2[o] = fmaxf(a, 0.f);
  }
  __syncthreads();
  for (int o = tid; o < 16; o += 256) {
    float a = bp3[0];
    for (int k = 0; k < 64; k++) a += t2[o * 64 + k] * Wp3[k];
    out_p[g0 + o] = a;
  }
  __syncthreads();
  for (int o = tid; o < 16 * 64; o += 256) {
    int r = o >> 6, c = o & 63;
    float a = bd1[c];
    for (int k = 0; k < 128; k++) a += es[r * 128 + k] * Wd1[k * 64 + c];
    t1[o] = fmaxf(a, 0.f);
  }
  __syncthreads();
  for (int o = tid; o < 16 * 2; o += 256) {
    int r = o >> 1, c = o & 1;
    float a = bd2[c];
    for (int k = 0; k < 64; k++) a += t1[r * 64 + k] * Wd2[k * 2 + c];
    out_d[(size_t)(g0 + r) * 2 + c] = a;
  }
}

// ---------------- launch ----------------

extern "C" void kernel_launch(void* const* d_in, const int* in_sizes, int n_in,
                              void* d_out, int out_size, void* d_ws, size_t ws_size,
                              hipStream_t stream) {
  const float* x   = (const float*)d_in[0];
  const int*   ei  = (const int*)d_in[1];
  const int*   bat = (const int*)d_in[2];
  const float* W1 = (const float*)d_in[3];  const float* b1  = (const float*)d_in[4];
  const float* g1 = (const float*)d_in[5];  const float* bt1 = (const float*)d_in[6];
  const float* W2 = (const float*)d_in[7];  const float* b2  = (const float*)d_in[8];
  const float* g2 = (const float*)d_in[9];  const float* bt2 = (const float*)d_in[10];
  const float* W3 = (const float*)d_in[11]; const float* b3  = (const float*)d_in[12];
  const float* Wo1 = (const float*)d_in[13]; const float* bo1 = (const float*)d_in[14];
  const float* Wo2 = (const float*)d_in[15]; const float* bo2 = (const float*)d_in[16];
  const float* Wp1 = (const float*)d_in[17]; const float* bp1 = (const float*)d_in[18];
  const float* Wp2 = (const float*)d_in[19]; const float* bp2 = (const float*)d_in[20];
  const float* Wp3 = (const float*)d_in[21]; const float* bp3 = (const float*)d_in[22];
  const float* Wd1 = (const float*)d_in[23]; const float* bd1 = (const float*)d_in[24];
  const float* Wd2 = (const float*)d_in[25]; const float* bd2 = (const float*)d_in[26];

  int N = in_sizes[0] / 20;
  int E = in_sizes[1] / 2;
  int B = out_size / 144;  // 13 + 1 + 2 + 128
  const int* esrc = ei;
  const int* edst = ei + E;
  int NB = (N + (1 << BSH) - 1) >> BSH;

  char* ws = (char*)d_ws;
  size_t off = 0;
  auto alloc = [&](size_t bytes) -> char* {
    char* p = ws + off;
    off = (off + bytes + 255) & ~(size_t)255;
    return p;
  };
  int*   gcur  = (int*)alloc((size_t)NB * 4);
  int*   deg   = (int*)alloc((size_t)N * 4);
  float* dinv  = (float*)alloc((size_t)N * 4);
  int*   offs  = (int*)alloc(((size_t)N + 1) * 4);
  int*   bsum  = (int*)alloc(128 * 4);
  int*   goffs = (int*)alloc(((size_t)B + 1) * 4);
  float* bn    = (float*)alloc(512 * 4);
  float* partial = (float*)alloc((size_t)SBLK * 128 * 4);
  unsigned long long* temp = (unsigned long long*)alloc((size_t)NB * CAP * 8);
  int*   csr   = (int*)alloc((size_t)E * 4);
  float* bufA  = (float*)alloc((size_t)N * 64 * 4);
  float* bufB  = (float*)alloc((size_t)N * 64 * 4);
  float* ep    = (float*)alloc((size_t)B * 64 * 4);

  float* ta1 = bn + 256, *tc1 = bn + 320;
  float* ta2 = bn + 384, *tc2 = bn + 448;

  float* out_op = (float*)d_out;
  float* out_p  = out_op + (size_t)B * 13;
  float* out_d  = out_p + B;
  float* enc    = out_d + (size_t)B * 2;

  hipLaunchKernelGGL(initk, dim3(2), dim3(256), 0, stream, gcur, bn, NB);
  hipLaunchKernelGGL(bound_kernel, dim3((N + 255) / 256), dim3(256), 0, stream, bat, goffs, N, B);
  hipLaunchKernelGGL(passA, dim3(256), dim3(256), 0, stream, edst, esrc, gcur, temp, E, NB);
  hipLaunchKernelGGL(passB1, dim3(NB), dim3(512), 0, stream, temp, gcur, deg, dinv, N);
  int nb1 = (N + 1023) / 1024;
  hipLaunchKernelGGL(scan_p1, dim3(nb1), dim3(1024), 0, stream, deg, offs, bsum, N);
  hipLaunchKernelGGL(scan_p2, dim3(1), dim3(128), 0, stream, bsum, nb1);
  hipLaunchKernelGGL(scan_p3, dim3(nb1), dim3(1024), 0, stream, offs, bsum, N, E);
  hipLaunchKernelGGL(passB2, dim3(NB), dim3(512), 0, stream, temp, gcur, offs, csr, N);

  int gblocks = (N + 127) / 128;
  // layer 1: fused gather(x*dinv) -> gemm(20->64) -> bn stats/final
  hipLaunchKernelGGL(agg32x_kernel, dim3(2048), dim3(256), 0, stream, x, offs, csr, dinv, bufA, N);
  hipLaunchKernelGGL((gemm_agg<20, 32>), dim3(gblocks), dim3(256), 0, stream,
                     bufA, W1, b1, dinv, bufB, N);
  hipLaunchKernelGGL(bn_stats, dim3(SBLK), dim3(256), 0, stream, bufB, partial, N);
  hipLaunchKernelGGL(bn_final_kernel, dim3(1), dim3(1024), 0, stream,
                     partial, g1, bt1, ta1, tc1, (float)N);
  // layer 2: fused transform+gather -> gemm -> bn stats/final
  hipLaunchKernelGGL((agg64t_kernel<false>), dim3(2048), dim3(256), 0, stream,
                     bufB, ta1, tc1, offs, csr, dinv, bufA, N);
  hipLaunchKernelGGL((gemm_agg<64, 64>), dim3(gblocks), dim3(256), 0, stream,
                     bufA, W2, b2, dinv, bufB, N);
  hipLaunchKernelGGL(bn_stats, dim3(SBLK), dim3(256), 0, stream, bufB, partial, N);
  hipLaunchKernelGGL(bn_final_kernel, dim3(1), dim3(1024), 0, stream,
                     partial, g2, bt2, ta2, tc2, (float)N);
  // layer 3: fused transform+gather (scaled) -> pool -> heads
  hipLaunchKernelGGL((agg64t_kernel<true>), dim3(2048), dim3(256), 0, stream,
                     bufB, ta2, tc2, offs, csr, dinv, bufA, N);
  hipLaunchKernelGGL(pool_kernel, dim3(B), dim3(64), 0, stream, bufA, goffs, ep, B);
  hipLaunchKernelGGL(heads_kernel, dim3(B / 16), dim3(256), 0, stream, ep, goffs, W3, b3,
                     Wo1, bo1, Wo2, bo2, Wp1, bp1, Wp2, bp2, Wp3, bp3, Wd1, bd1, Wd2, bd2,
                     out_op, out_p, out_d, enc, B);
}

// Round 9
// 496.579 us; speedup vs baseline: 1.3409x; 1.0729x over previous
//
#include <hip/hip_runtime.h>

#define BN_EPS 1e-5f

constexpr int BSH = 9;          // 512 nodes per bucket
constexpr int MAXB = 200;       // max buckets supported (N <= 102400)
constexpr int CAP = 12288;      // temp capacity (pairs) per bucket
constexpr int BINCAP = 32;      // LDS bin capacity per bucket (pairs)
constexpr int FLUSH = 16;       // flush granularity (pairs)
constexpr int SBLK = 256;       // bn_stats grid (bn_final assumes 256 partials)

typedef unsigned short u16;
typedef unsigned int u32;

__device__ __forceinline__ float b2f(u16 h) {
  return __uint_as_float(((u32)h) << 16);
}
__device__ __forceinline__ u16 f2b(float f) {  // round-to-nearest-even
  u32 u = __float_as_uint(f);
  return (u16)((u + 0x7FFFu + ((u >> 16) & 1u)) >> 16);
}

// ---------------- init ----------------

__global__ void initk(int* __restrict__ gcur, float* __restrict__ bn, int NB) {
  int t = blockIdx.x * blockDim.x + threadIdx.x;
  if (t < NB) gcur[t] = t * CAP;
  if (t < 512) bn[t] = 0.f;
}

// goffs from sorted batch
__global__ void bound_kernel(const int* __restrict__ batch, int* __restrict__ goffs, int N, int B) {
  int i = blockIdx.x * blockDim.x + threadIdx.x;
  if (i < N) {
    int b = batch[i];
    int p = (i == 0) ? -1 : batch[i - 1];
    for (int g = p + 1; g <= b; ++g) goffs[g] = i;
    if (i == N - 1) {
      for (int g = b + 1; g <= B; ++g) goffs[g] = N;
    }
  }
}

// ---------------- bucketed CSR build ----------------

__global__ __launch_bounds__(256) void passA(const int* __restrict__ dst, const int* __restrict__ src,
                                             int* __restrict__ gcur, unsigned long long* __restrict__ temp,
                                             int E, int NB) {
  __shared__ unsigned long long bins[MAXB * BINCAP];
  __shared__ int bcnt[MAXB];
  int tid = threadIdx.x;
  for (int b = tid; b < NB; b += 256) bcnt[b] = 0;
  __syncthreads();
  int chunk = (E + gridDim.x - 1) / gridDim.x;
  int e0 = blockIdx.x * chunk;
  int e1 = min(e0 + chunk, E);
  for (int base = e0; base < e1; base += 1024) {
#pragma unroll
    for (int j = 0; j < 4; ++j) {
      int e = base + tid * 4 + j;
      if (e < e1) {
        int d = dst[e];
        int s = src[e];
        int b = d >> BSH;
        unsigned long long pk = ((unsigned long long)(unsigned)s << 32) | (unsigned)d;
        int slot = atomicAdd(&bcnt[b], 1);
        if (slot < BINCAP) {
          bins[b * BINCAP + slot] = pk;
        } else {
          int p = atomicAdd(&gcur[b], 1);
          temp[p] = pk;
        }
      }
    }
    __syncthreads();
    if (tid < NB) {
      int c = min(bcnt[tid], BINCAP);
      while (c >= FLUSH) {
        int p = atomicAdd(&gcur[tid], FLUSH);
        for (int j = 0; j < FLUSH; ++j) temp[p + j] = bins[tid * BINCAP + j];
        c -= FLUSH;
        for (int j = 0; j < c; ++j) bins[tid * BINCAP + j] = bins[tid * BINCAP + FLUSH + j];
      }
      bcnt[tid] = c;
    }
    __syncthreads();
  }
  if (tid < NB) {
    int c = min(bcnt[tid], BINCAP);
    if (c > 0) {
      int p = atomicAdd(&gcur[tid], c);
      for (int j = 0; j < c; ++j) temp[p + j] = bins[tid * BINCAP + j];
    }
  }
}

__global__ __launch_bounds__(512) void passB1(const unsigned long long* __restrict__ temp,
                                              const int* __restrict__ gcur,
                                              int* __restrict__ deg, float* __restrict__ dinv, int N) {
  __shared__ int h[512];
  int b = blockIdx.x, t = threadIdx.x;
  h[t] = 0;
  __syncthreads();
  int cnt = min(gcur[b] - b * CAP, CAP);
  const unsigned long long* tp = temp + (size_t)b * CAP;
  for (int i = t; i < cnt; i += 512) {
    int d = (int)(tp[i] & 0xffffffffu);
    atomicAdd(&h[d & 511], 1);
  }
  __syncthreads();
  int node = (b << BSH) + t;
  if (node < N) {
    deg[node] = h[t];
    dinv[node] = rsqrtf((float)h[t] + 1.f);
  }
}

__global__ __launch_bounds__(512) void passB2(const unsigned long long* __restrict__ temp,
                                              const int* __restrict__ gcur,
                                              const int* __restrict__ offs,
                                              int* __restrict__ csr, int N) {
  __shared__ int lofs[512];
  __shared__ int lcnt[512];
  int b = blockIdx.x, t = threadIdx.x;
  int node = (b << BSH) + t;
  lofs[t] = offs[min(node, N)];
  lcnt[t] = 0;
  __syncthreads();
  int cnt = min(gcur[b] - b * CAP, CAP);
  const unsigned long long* tp = temp + (size_t)b * CAP;
  for (int i = t; i < cnt; i += 512) {
    unsigned long long pk = tp[i];
    int d = (int)(pk & 0xffffffffu) & 511;
    int s = (int)(pk >> 32);
    int pos = lofs[d] + atomicAdd(&lcnt[d], 1);
    csr[pos] = s;
  }
}

// ---------------- 3-phase exclusive scan ----------------

__global__ __launch_bounds__(1024) void scan_p1(const int* __restrict__ cnt,
                                                int* __restrict__ offs,
                                                int* __restrict__ bsum, int n) {
  __shared__ int sh[1024];
  int t = threadIdx.x;
  int i = blockIdx.x * 1024 + t;
  int v = (i < n) ? cnt[i] : 0;
  sh[t] = v;
  __syncthreads();
  for (int d = 1; d < 1024; d <<= 1) {
    int x = (t >= d) ? sh[t - d] : 0;
    __syncthreads();
    sh[t] += x;
    __syncthreads();
  }
  if (i < n) offs[i] = sh[t] - v;
  if (t == 1023) bsum[blockIdx.x] = sh[t];
}

__global__ void scan_p2(int* __restrict__ bsum, int nb) {
  __shared__ int sh[128];
  int t = threadIdx.x;
  int v = (t < nb) ? bsum[t] : 0;
  sh[t] = v;
  __syncthreads();
  for (int d = 1; d < 128; d <<= 1) {
    int x = (t >= d) ? sh[t - d] : 0;
    __syncthreads();
    sh[t] += x;
    __syncthreads();
  }
  if (t < nb) bsum[t] = sh[t] - v;
}

__global__ __launch_bounds__(1024) void scan_p3(int* __restrict__ offs,
                                                const int* __restrict__ bsum, int n, int E) {
  int i = blockIdx.x * 1024 + threadIdx.x;
  if (i < n) offs[i] += bsum[blockIdx.x];
  if (i == 0) offs[n] = E;
}

// ---------------- pre-pass: x16[i][f] = bf16(x[i][f]*dinv[i]), padded 20->32 ----------------

__global__ void prex_kernel(const float* __restrict__ x, const float* __restrict__ dinv,
                            u16* __restrict__ x16, int N) {
  int stride = gridDim.x * blockDim.x;
  for (int i = blockIdx.x * blockDim.x + threadIdx.x; i < N * 32; i += stride) {
    int row = i >> 5, f = i & 31;
    float v = (f < 20) ? x[row * 20 + f] * dinv[row] : 0.f;
    x16[i] = f2b(v);
  }
}

// ---------------- aggregation over bf16 rows ----------------

// layer 1: 32-wide bf16 rows (dinv pre-folded); 2 rows per wave iteration
__global__ __launch_bounds__(256) void agg32x_kernel(const u16* __restrict__ x16,
                                                     const int* __restrict__ offs,
                                                     const int* __restrict__ csr,
                                                     float* __restrict__ out, int n) {
  int lane = threadIdx.x & 63;
  int wid = threadIdx.x >> 6;
  int half = lane >> 5, f = lane & 31;
  int gw = blockIdx.x * 4 + wid, nw = gridDim.x * 4;
  for (int i = gw; i < n; i += nw) {
    float acc = half ? 0.f : b2f(x16[(size_t)i * 32 + f]);
    int st = offs[i], en = offs[i + 1];
    for (int base = st; base < en; base += 64) {
      int idx = base + lane;
      int v = (idx < en) ? csr[idx] : 0;
      int cnt = min(64, en - base);
      int j = 0;
      for (; j + 3 < cnt; j += 4) {
        int s0 = __shfl(v, j + half);
        int s1 = __shfl(v, j + 2 + half);
        acc += b2f(x16[(size_t)s0 * 32 + f]) + b2f(x16[(size_t)s1 * 32 + f]);
      }
      for (; j < cnt; ++j) {
        int s = __shfl(v, j);
        if (!half) acc += b2f(x16[(size_t)s * 32 + f]);
      }
    }
    acc += __shfl_xor(acc, 32);
    if (!half) out[(size_t)i * 32 + f] = acc;
  }
}

// layers 2/3: bf16 z rows, T(v,row) = relu(v*ta+tc)*dinv[row] on the fly
template <bool SCALE>
__global__ __launch_bounds__(256) void agg64t_kernel(const u16* __restrict__ z16,
                                                     const float* __restrict__ tav,
                                                     const float* __restrict__ tcv,
                                                     const int* __restrict__ offs,
                                                     const int* __restrict__ csr,
                                                     const float* __restrict__ dinv,
                                                     float* __restrict__ out, int n) {
  int lane = threadIdx.x & 63;
  int wid = threadIdx.x >> 6;
  float ta = tav[lane], tc = tcv[lane];
  int gw = blockIdx.x * 4 + wid, nw = gridDim.x * 4;
  for (int i = gw; i < n; i += nw) {
    float di = dinv[i];
    float acc = fmaxf(b2f(z16[(size_t)i * 64 + lane]) * ta + tc, 0.f) * di;
    int st = offs[i], en = offs[i + 1];
    for (int base = st; base < en; base += 64) {
      int idx = base + lane;
      int v = (idx < en) ? csr[idx] : 0;
      int cnt = min(64, en - base);
      int j = 0;
      for (; j + 3 < cnt; j += 4) {
        int s0 = __shfl(v, j), s1 = __shfl(v, j + 1);
        int s2 = __shfl(v, j + 2), s3 = __shfl(v, j + 3);
        float d0 = dinv[s0], d1 = dinv[s1], d2 = dinv[s2], d3 = dinv[s3];
        acc += fmaxf(b2f(z16[(size_t)s0 * 64 + lane]) * ta + tc, 0.f) * d0 +
               fmaxf(b2f(z16[(size_t)s1 * 64 + lane]) * ta + tc, 0.f) * d1 +
               fmaxf(b2f(z16[(size_t)s2 * 64 + lane]) * ta + tc, 0.f) * d2 +
               fmaxf(b2f(z16[(size_t)s3 * 64 + lane]) * ta + tc, 0.f) * d3;
      }
      for (; j < cnt; ++j) {
        int s = __shfl(v, j);
        acc += fmaxf(b2f(z16[(size_t)s * 64 + lane]) * ta + tc, 0.f) * dinv[s];
      }
    }
    if (SCALE) acc *= di;
    out[(size_t)i * 64 + lane] = acc;
  }
}

// ---------------- GEMM: z16 = bf16(dinv*(a@W) + bias) ----------------

template <int K, int AS>
__global__ __launch_bounds__(256) void gemm_agg(const float* __restrict__ A, const float* __restrict__ W,
                                                const float* __restrict__ bias, const float* __restrict__ dinv,
                                                u16* __restrict__ z16, int n) {
  __shared__ float Ws[K * 64];
  __shared__ float As[128 * (K + 1)];
  int tid = threadIdx.x;
  int row0 = blockIdx.x * 128;
  for (int i = tid; i < K * 64; i += 256) Ws[i] = W[i];
  for (int i = tid; i < 128 * K; i += 256) {
    int r = i / K, k = i - r * K;
    int gr = row0 + r;
    As[r * (K + 1) + k] = (gr < n) ? A[(size_t)gr * AS + k] : 0.f;
  }
  __syncthreads();
  int rg = tid >> 2;
  int fs = tid & 3;
  float acc0[16], acc1[16];
#pragma unroll
  for (int j = 0; j < 16; ++j) { acc0[j] = 0.f; acc1[j] = 0.f; }
  const float* a0 = &As[(2 * rg) * (K + 1)];
  const float* a1 = &As[(2 * rg + 1) * (K + 1)];
  const float* wb = &Ws[fs * 16];
  for (int k = 0; k < K; ++k) {
    float x0 = a0[k], x1 = a1[k];
#pragma unroll
    for (int j = 0; j < 16; ++j) {
      float w = wb[k * 64 + j];
      acc0[j] += x0 * w;
      acc1[j] += x1 * w;
    }
  }
  int base = fs * 16;
  int r0 = row0 + 2 * rg;
  if (r0 < n) {
    float dv = dinv[r0];
    u32 pk[8];
#pragma unroll
    for (int j = 0; j < 8; ++j) {
      float o0 = acc0[2 * j] * dv + bias[base + 2 * j];
      float o1 = acc0[2 * j + 1] * dv + bias[base + 2 * j + 1];
      pk[j] = (u32)f2b(o0) | ((u32)f2b(o1) << 16);
    }
    uint4* zp = (uint4*)&z16[(size_t)r0 * 64 + base];
    zp[0] = make_uint4(pk[0], pk[1], pk[2], pk[3]);
    zp[1] = make_uint4(pk[4], pk[5], pk[6], pk[7]);
  }
  int r1 = r0 + 1;
  if (r1 < n) {
    float dv = dinv[r1];
    u32 pk[8];
#pragma unroll
    for (int j = 0; j < 8; ++j) {
      float o0 = acc1[2 * j] * dv + bias[base + 2 * j];
      float o1 = acc1[2 * j + 1] * dv + bias[base + 2 * j + 1];
      pk[j] = (u32)f2b(o0) | ((u32)f2b(o1) << 16);
    }
    uint4* zp = (uint4*)&z16[(size_t)r1 * 64 + base];
    zp[0] = make_uint4(pk[0], pk[1], pk[2], pk[3]);
    zp[1] = make_uint4(pk[4], pk[5], pk[6], pk[7]);
  }
}

// ---------------- BN stats over bf16 z ----------------

__global__ __launch_bounds__(256) void bn_stats(const u16* __restrict__ z16,
                                                float* __restrict__ partial, int N) {
  int lane = threadIdx.x & 63, wid = threadIdx.x >> 6;
  int gw = blockIdx.x * 4 + wid, nw = gridDim.x * 4;
  float s = 0.f, q = 0.f;
  for (int r = gw; r < N; r += nw) {
    float v = b2f(z16[(size_t)r * 64 + lane]);
    s += v;
    q += v * v;
  }
  __shared__ float sh[2][4][64];
  sh[0][wid][lane] = s;
  sh[1][wid][lane] = q;
  __syncthreads();
  if (wid == 0) {
    float ts = sh[0][0][lane] + sh[0][1][lane] + sh[0][2][lane] + sh[0][3][lane];
    float tq = sh[1][0][lane] + sh[1][1][lane] + sh[1][2][lane] + sh[1][3][lane];
    partial[blockIdx.x * 128 + lane] = ts;
    partial[blockIdx.x * 128 + 64 + lane] = tq;
  }
}

// parallel finalize: 1024 threads = 16 groups x 64 lanes
__global__ __launch_bounds__(1024) void bn_final_kernel(const float* __restrict__ partial,
                                                        const float* __restrict__ g,
                                                        const float* __restrict__ bt,
                                                        float* __restrict__ a, float* __restrict__ c,
                                                        float n) {
  __shared__ float sh[16][128];
  int t = threadIdx.x;
  int grp = t >> 6, lane = t & 63;
  float s = 0.f, q = 0.f;
#pragma unroll
  for (int k = 0; k < 16; ++k) {
    int i = grp * 16 + k;
    s += partial[i * 128 + lane];
    q += partial[i * 128 + 64 + lane];
  }
  sh[grp][lane] = s;
  sh[grp][64 + lane] = q;
  __syncthreads();
  for (int str = 8; str >= 1; str >>= 1) {
    if (grp < str) {
      sh[grp][lane] += sh[grp + str][lane];
      sh[grp][64 + lane] += sh[grp + str][64 + lane];
    }
    __syncthreads();
  }
  if (grp == 0) {
    float mu = sh[0][lane] / n;
    float var = fmaxf(sh[0][64 + lane] / n - mu * mu, 0.f);
    float rstd = rsqrtf(var + BN_EPS);
    float av = g[lane] * rstd;
    a[lane] = av;
    c[lane] = bt[lane] - mu * av;
  }
}

// ---------------- pool ----------------

__global__ __launch_bounds__(64) void pool_kernel(const float* __restrict__ v3,
                                                  const int* __restrict__ goffs,
                                                  float* __restrict__ ep, int B) {
  int b = blockIdx.x, t = threadIdx.x;
  int st = goffs[b], en = goffs[b + 1];
  float s = 0.f;
  int r = st;
  for (; r + 1 < en; r += 2) s += v3[(size_t)r * 64 + t] + v3[(size_t)(r + 1) * 64 + t];
  if (r < en) s += v3[(size_t)r * 64 + t];
  int c = en - st;
  ep[(size_t)b * 64 + t] = s / (float)max(c, 1);
}

// ---------------- heads ----------------

__global__ __launch_bounds__(256) void heads_kernel(
    const float* __restrict__ ep, const int* __restrict__ goffs,
    const float* __restrict__ W3, const float* __restrict__ b3,
    const float* __restrict__ Wo1, const float* __restrict__ bo1,
    const float* __restrict__ Wo2, const float* __restrict__ bo2,
    const float* __restrict__ Wp1, const float* __restrict__ bp1,
    const float* __restrict__ Wp2, const float* __restrict__ bp2,
    const float* __restrict__ Wp3, const float* __restrict__ bp3,
    const float* __restrict__ Wd1, const float* __restrict__ bd1,
    const float* __restrict__ Wd2, const float* __restrict__ bd2,
    float* __restrict__ out_op, float* __restrict__ out_p, float* __restrict__ out_d,
    float* __restrict__ enc_out, int B) {
  __shared__ float epl[16 * 64];
  __shared__ float es[16 * 128];
  __shared__ float t1[16 * 64];
  __shared__ float t2[16 * 64];
  int tid = threadIdx.x;
  int g0 = blockIdx.x * 16;
  for (int i = tid; i < 16 * 64; i += 256) epl[i] = ep[(size_t)g0 * 64 + i];
  __syncthreads();
  for (int o = tid; o < 16 * 128; o += 256) {
    int r = o >> 7, c = o & 127;
    float a = b3[c];
    for (int k = 0; k < 64; ++k) a += epl[r * 64 + k] * W3[k * 128 + c];
    if (goffs[g0 + r + 1] - goffs[g0 + r] == 0) a = 0.f;
    es[o] = a;
    enc_out[(size_t)(g0 + r) * 128 + c] = a;
  }
  __syncthreads();
  for (int o = tid; o < 16 * 64; o += 256) {
    int r = o >> 6, c = o & 63;
    float a = bo1[c];
    for (int k = 0; k < 128; k++) a += es[r * 128 + k] * Wo1[k * 64 + c];
    t1[o] = fmaxf(a, 0.f);
  }
  __syncthreads();
  for (int o = tid; o < 16 * 13; o += 256) {
    int r = o / 13, c = o - r * 13;
    float a = bo2[c];
    for (int k = 0; k < 64; k++) a += t1[r * 64 + k] * Wo2[k * 13 + c];
    out_op[(size_t)(g0 + r) * 13 + c] = a;
  }
  __syncthreads();
  for (int o = tid; o < 16 * 64; o += 256) {
    int r = o >> 6, c = o & 63;
    float a = bp1[c];
    for (int k = 0; k < 128; k++) a += es[r * 128 + k] * Wp1[k * 64 + c];
    t1[o] = fmaxf(a, 0.f);
  }
  __syncthreads();
  for (int o = tid; o < 16 * 64; o += 256) {
    int r = o >> 6, c = o & 63;
    float a = bp2[c];
    for (int k = 0; k < 64; k++) a += t1[r * 64 + k] * Wp2[k * 64 + c];
    t2[o] = fmaxf(a, 0.f);
  }
  __syncthreads();
  for (int o = tid; o < 16; o += 256) {
    float a = bp3[0];
    for (int k = 0; k < 64; k++) a += t2[o * 64 + k] * Wp3[k];
    out_p[g0 + o] = a;
  }
  __syncthreads();
  for (int o = tid; o < 16 * 64; o += 256) {
    int r = o >> 6, c = o & 63;
    float a = bd1[c];
    for (int k = 0; k < 128; k++) a += es[r * 128 + k] * Wd1[k * 64 + c];
    t1[o] = fmaxf(a, 0.f);
  }
  __syncthreads();
  for (int o = tid; o < 16 * 2; o += 256) {
    int r = o >> 1, c = o & 1;
    float a = bd2[c];
    for (int k = 0; k < 64; k++) a += t1[r * 64 + k] * Wd2[k * 2 + c];
    out_d[(size_t)(g0 + r) * 2 + c] = a;
  }
}

// ---------------- launch ----------------

extern "C" void kernel_launch(void* const* d_in, const int* in_sizes, int n_in,
                              void* d_out, int out_size, void* d_ws, size_t ws_size,
                              hipStream_t stream) {
  const float* x   = (const float*)d_in[0];
  const int*   ei  = (const int*)d_in[1];
  const int*   bat = (const int*)d_in[2];
  const float* W1 = (const float*)d_in[3];  const float* b1  = (const float*)d_in[4];
  const float* g1 = (const float*)d_in[5];  const float* bt1 = (const float*)d_in[6];
  const float* W2 = (const float*)d_in[7];  const float* b2  = (const float*)d_in[8];
  const float* g2 = (const float*)d_in[9];  const float* bt2 = (const float*)d_in[10];
  const float* W3 = (const float*)d_in[11]; const float* b3  = (const float*)d_in[12];
  const float* Wo1 = (const float*)d_in[13]; const float* bo1 = (const float*)d_in[14];
  const float* Wo2 = (const float*)d_in[15]; const float* bo2 = (const float*)d_in[16];
  const float* Wp1 = (const float*)d_in[17]; const float* bp1 = (const float*)d_in[18];
  const float* Wp2 = (const float*)d_in[19]; const float* bp2 = (const float*)d_in[20];
  const float* Wp3 = (const float*)d_in[21]; const float* bp3 = (const float*)d_in[22];
  const float* Wd1 = (const float*)d_in[23]; const float* bd1 = (const float*)d_in[24];
  const float* Wd2 = (const float*)d_in[25]; const float* bd2 = (const float*)d_in[26];

  int N = in_sizes[0] / 20;
  int E = in_sizes[1] / 2;
  int B = out_size / 144;  // 13 + 1 + 2 + 128
  const int* esrc = ei;
  const int* edst = ei + E;
  int NB = (N + (1 << BSH) - 1) >> BSH;

  char* ws = (char*)d_ws;
  size_t off = 0;
  auto alloc = [&](size_t bytes) -> char* {
    char* p = ws + off;
    off = (off + bytes + 255) & ~(size_t)255;
    return p;
  };
  int*   gcur  = (int*)alloc((size_t)NB * 4);
  int*   deg   = (int*)alloc((size_t)N * 4);
  float* dinv  = (float*)alloc((size_t)N * 4);
  int*   offs  = (int*)alloc(((size_t)N + 1) * 4);
  int*   bsum  = (int*)alloc(128 * 4);
  int*   goffs = (int*)alloc(((size_t)B + 1) * 4);
  float* bn    = (float*)alloc(512 * 4);
  float* partial = (float*)alloc((size_t)SBLK * 128 * 4);
  unsigned long long* temp = (unsigned long long*)alloc((size_t)NB * CAP * 8);
  int*   csr   = (int*)alloc((size_t)E * 4);
  u16*   x16   = (u16*)alloc((size_t)N * 32 * 2);
  u16*   z16   = (u16*)alloc((size_t)N * 64 * 2);
  float* aggf  = (float*)alloc((size_t)N * 64 * 4);
  float* ep    = (float*)alloc((size_t)B * 64 * 4);

  float* ta1 = bn + 256, *tc1 = bn + 320;
  float* ta2 = bn + 384, *tc2 = bn + 448;

  float* out_op = (float*)d_out;
  float* out_p  = out_op + (size_t)B * 13;
  float* out_d  = out_p + B;
  float* enc    = out_d + (size_t)B * 2;

  hipLaunchKernelGGL(initk, dim3(2), dim3(256), 0, stream, gcur, bn, NB);
  hipLaunchKernelGGL(bound_kernel, dim3((N + 255) / 256), dim3(256), 0, stream, bat, goffs, N, B);
  hipLaunchKernelGGL(passA, dim3(256), dim3(256), 0, stream, edst, esrc, gcur, temp, E, NB);
  hipLaunchKernelGGL(passB1, dim3(NB), dim3(512), 0, stream, temp, gcur, deg, dinv, N);
  int nb1 = (N + 1023) / 1024;
  hipLaunchKernelGGL(scan_p1, dim3(nb1), dim3(1024), 0, stream, deg, offs, bsum, N);
  hipLaunchKernelGGL(scan_p2, dim3(1), dim3(128), 0, stream, bsum, nb1);
  hipLaunchKernelGGL(scan_p3, dim3(nb1), dim3(1024), 0, stream, offs, bsum, N, E);
  hipLaunchKernelGGL(passB2, dim3(NB), dim3(512), 0, stream, temp, gcur, offs, csr, N);

  int gblocks = (N + 127) / 128;
  // layer 1: prex (x*dinv -> bf16) -> gather -> gemm(20->64) -> bn
  hipLaunchKernelGGL(prex_kernel, dim3(2048), dim3(256), 0, stream, x, dinv, x16, N);
  hipLaunchKernelGGL(agg32x_kernel, dim3(2048), dim3(256), 0, stream, x16, offs, csr, aggf, N);
  hipLaunchKernelGGL((gemm_agg<20, 32>), dim3(gblocks), dim3(256), 0, stream,
                     aggf, W1, b1, dinv, z16, N);
  hipLaunchKernelGGL(bn_stats, dim3(SBLK), dim3(256), 0, stream, z16, partial, N);
  hipLaunchKernelGGL(bn_final_kernel, dim3(1), dim3(1024), 0, stream,
                     partial, g1, bt1, ta1, tc1, (float)N);
  // layer 2: fused transform+gather -> gemm -> bn
  hipLaunchKernelGGL((agg64t_kernel<false>), dim3(2048), dim3(256), 0, stream,
                     z16, ta1, tc1, offs, csr, dinv, aggf, N);
  hipLaunchKernelGGL((gemm_agg<64, 64>), dim3(gblocks), dim3(256), 0, stream,
                     aggf, W2, b2, dinv, z16, N);
  hipLaunchKernelGGL(bn_stats, dim3(SBLK), dim3(256), 0, stream, z16, partial, N);
  hipLaunchKernelGGL(bn_final_kernel, dim3(1), dim3(1024), 0, stream,
                     partial, g2, bt2, ta2, tc2, (float)N);
  // layer 3: fused transform+gather (scaled) -> pool -> heads
  hipLaunchKernelGGL((agg64t_kernel<true>), dim3(2048), dim3(256), 0, stream,
                     z16, ta2, tc2, offs, csr, dinv, aggf, N);
  hipLaunchKernelGGL(pool_kernel, dim3(B), dim3(64), 0, stream, aggf, goffs, ep, B);
  hipLaunchKernelGGL(heads_kernel, dim3(B / 16), dim3(256), 0, stream, ep, goffs, W3, b3,
                     Wo1, bo1, Wo2, bo2, Wp1, bp1, Wp2, bp2, Wp3, bp3, Wd1, bd1, Wd2, bd2,
                     out_op, out_p, out_d, enc, B);
}

// Round 10
// 479.615 us; speedup vs baseline: 1.3884x; 1.0354x over previous
//
#include <hip/hip_runtime.h>

#define BN_EPS 1e-5f

constexpr int BSH = 9;          // 512 nodes per bucket
constexpr int MAXB = 200;       // max buckets supported (N <= 102400)
constexpr int CAP = 12288;      // temp capacity (pairs) per bucket
constexpr int BINCAP = 32;      // LDS bin capacity per bucket (pairs)
constexpr int FLUSH = 16;       // flush granularity (pairs)

typedef unsigned short u16;
typedef unsigned int u32;

__device__ __forceinline__ float b2f(u16 h) {
  return __uint_as_float(((u32)h) << 16);
}
__device__ __forceinline__ u16 f2b(float f) {  // round-to-nearest-even
  u32 u = __float_as_uint(f);
  return (u16)((u + 0x7FFFu + ((u >> 16) & 1u)) >> 16);
}

// ---------------- goffs from sorted batch + gcur init ----------------

__global__ void bound_kernel(const int* __restrict__ batch, int* __restrict__ goffs,
                             int* __restrict__ gcur, int N, int B, int NB) {
  int i = blockIdx.x * blockDim.x + threadIdx.x;
  if (i < NB) gcur[i] = i * CAP;
  if (i < N) {
    int b = batch[i];
    int p = (i == 0) ? -1 : batch[i - 1];
    for (int g = p + 1; g <= b; ++g) goffs[g] = i;
    if (i == N - 1) {
      for (int g = b + 1; g <= B; ++g) goffs[g] = N;
    }
  }
}

// ---------------- bucketed CSR build ----------------

__global__ __launch_bounds__(256) void passA(const int* __restrict__ dst, const int* __restrict__ src,
                                             int* __restrict__ gcur, unsigned long long* __restrict__ temp,
                                             int E, int NB) {
  __shared__ unsigned long long bins[MAXB * BINCAP];
  __shared__ int bcnt[MAXB];
  int tid = threadIdx.x;
  for (int b = tid; b < NB; b += 256) bcnt[b] = 0;
  __syncthreads();
  int chunk = (E + gridDim.x - 1) / gridDim.x;
  int e0 = blockIdx.x * chunk;
  int e1 = min(e0 + chunk, E);
  for (int base = e0; base < e1; base += 1024) {
#pragma unroll
    for (int j = 0; j < 4; ++j) {
      int e = base + tid * 4 + j;
      if (e < e1) {
        int d = dst[e];
        int s = src[e];
        int b = d >> BSH;
        unsigned long long pk = ((unsigned long long)(unsigned)s << 32) | (unsigned)d;
        int slot = atomicAdd(&bcnt[b], 1);
        if (slot < BINCAP) {
          bins[b * BINCAP + slot] = pk;
        } else {
          int p = atomicAdd(&gcur[b], 1);
          temp[p] = pk;
        }
      }
    }
    __syncthreads();
    if (tid < NB) {
      int c = min(bcnt[tid], BINCAP);
      while (c >= FLUSH) {
        int p = atomicAdd(&gcur[tid], FLUSH);
        for (int j = 0; j < FLUSH; ++j) temp[p + j] = bins[tid * BINCAP + j];
        c -= FLUSH;
        for (int j = 0; j < c; ++j) bins[tid * BINCAP + j] = bins[tid * BINCAP + FLUSH + j];
      }
      bcnt[tid] = c;
    }
    __syncthreads();
  }
  if (tid < NB) {
    int c = min(bcnt[tid], BINCAP);
    if (c > 0) {
      int p = atomicAdd(&gcur[tid], c);
      for (int j = 0; j < c; ++j) temp[p + j] = bins[tid * BINCAP + j];
    }
  }
}

__global__ __launch_bounds__(512) void passB1(const unsigned long long* __restrict__ temp,
                                              const int* __restrict__ gcur,
                                              int* __restrict__ deg, float* __restrict__ dinv, int N) {
  __shared__ int h[512];
  int b = blockIdx.x, t = threadIdx.x;
  h[t] = 0;
  __syncthreads();
  int cnt = min(gcur[b] - b * CAP, CAP);
  const unsigned long long* tp = temp + (size_t)b * CAP;
  for (int i = t; i < cnt; i += 512) {
    int d = (int)(tp[i] & 0xffffffffu);
    atomicAdd(&h[d & 511], 1);
  }
  __syncthreads();
  int node = (b << BSH) + t;
  if (node < N) {
    deg[node] = h[t];
    dinv[node] = rsqrtf((float)h[t] + 1.f);
  }
}

__global__ __launch_bounds__(512) void passB2(const unsigned long long* __restrict__ temp,
                                              const int* __restrict__ gcur,
                                              const int* __restrict__ offs,
                                              int* __restrict__ csr, int N) {
  __shared__ int lofs[512];
  __shared__ int lcnt[512];
  int b = blockIdx.x, t = threadIdx.x;
  int node = (b << BSH) + t;
  lofs[t] = offs[min(node, N)];
  lcnt[t] = 0;
  __syncthreads();
  int cnt = min(gcur[b] - b * CAP, CAP);
  const unsigned long long* tp = temp + (size_t)b * CAP;
  for (int i = t; i < cnt; i += 512) {
    unsigned long long pk = tp[i];
    int d = (int)(pk & 0xffffffffu) & 511;
    int s = (int)(pk >> 32);
    int pos = lofs[d] + atomicAdd(&lcnt[d], 1);
    csr[pos] = s;
  }
}

// ---------------- 3-phase exclusive scan ----------------

__global__ __launch_bounds__(1024) void scan_p1(const int* __restrict__ cnt,
                                                int* __restrict__ offs,
                                                int* __restrict__ bsum, int n) {
  __shared__ int sh[1024];
  int t = threadIdx.x;
  int i = blockIdx.x * 1024 + t;
  int v = (i < n) ? cnt[i] : 0;
  sh[t] = v;
  __syncthreads();
  for (int d = 1; d < 1024; d <<= 1) {
    int x = (t >= d) ? sh[t - d] : 0;
    __syncthreads();
    sh[t] += x;
    __syncthreads();
  }
  if (i < n) offs[i] = sh[t] - v;
  if (t == 1023) bsum[blockIdx.x] = sh[t];
}

__global__ void scan_p2(int* __restrict__ bsum, int nb) {
  __shared__ int sh[128];
  int t = threadIdx.x;
  int v = (t < nb) ? bsum[t] : 0;
  sh[t] = v;
  __syncthreads();
  for (int d = 1; d < 128; d <<= 1) {
    int x = (t >= d) ? sh[t - d] : 0;
    __syncthreads();
    sh[t] += x;
    __syncthreads();
  }
  if (t < nb) bsum[t] = sh[t] - v;
}

__global__ __launch_bounds__(1024) void scan_p3(int* __restrict__ offs,
                                                const int* __restrict__ bsum, int n, int E) {
  int i = blockIdx.x * 1024 + threadIdx.x;
  if (i < n) offs[i] += bsum[blockIdx.x];
  if (i == 0) offs[n] = E;
}

// ---------------- pre-pass: x16[i][f] = bf16(x[i][f]*dinv[i]), padded 20->32 ----------------

__global__ void prex_kernel(const float* __restrict__ x, const float* __restrict__ dinv,
                            u16* __restrict__ x16, int N) {
  int stride = gridDim.x * blockDim.x;
  for (int i = blockIdx.x * blockDim.x + threadIdx.x; i < N * 32; i += stride) {
    int row = i >> 5, f = i & 31;
    float v = (f < 20) ? x[row * 20 + f] * dinv[row] : 0.f;
    x16[i] = f2b(v);
  }
}

// ---------------- aggregation over bf16 rows ----------------

// layer 1: 32-wide bf16 rows (dinv pre-folded); 2 rows per wave iteration
__global__ __launch_bounds__(256) void agg32x_kernel(const u16* __restrict__ x16,
                                                     const int* __restrict__ offs,
                                                     const int* __restrict__ csr,
                                                     float* __restrict__ out, int n) {
  int lane = threadIdx.x & 63;
  int wid = threadIdx.x >> 6;
  int half = lane >> 5, f = lane & 31;
  int gw = blockIdx.x * 4 + wid, nw = gridDim.x * 4;
  for (int i = gw; i < n; i += nw) {
    float acc = half ? 0.f : b2f(x16[(size_t)i * 32 + f]);
    int st = offs[i], en = offs[i + 1];
    for (int base = st; base < en; base += 64) {
      int idx = base + lane;
      int v = (idx < en) ? csr[idx] : 0;
      int cnt = min(64, en - base);
      int j = 0;
      for (; j + 3 < cnt; j += 4) {
        int s0 = __shfl(v, j + half);
        int s1 = __shfl(v, j + 2 + half);
        acc += b2f(x16[(size_t)s0 * 32 + f]) + b2f(x16[(size_t)s1 * 32 + f]);
      }
      for (; j < cnt; ++j) {
        int s = __shfl(v, j);
        if (!half) acc += b2f(x16[(size_t)s * 32 + f]);
      }
    }
    acc += __shfl_xor(acc, 32);
    if (!half) out[(size_t)i * 32 + f] = acc;
  }
}

// layers 2/3: bf16 z rows; neighbor index made wave-uniform (readfirstlane) so the
// gather uses an SGPR base (scalar address math) and dinv[s] becomes an s_load.
template <bool SCALE>
__global__ __launch_bounds__(256) void agg64t_kernel(const u16* __restrict__ z16,
                                                     const float* __restrict__ tav,
                                                     const float* __restrict__ tcv,
                                                     const int* __restrict__ offs,
                                                     const int* __restrict__ csr,
                                                     const float* __restrict__ dinv,
                                                     float* __restrict__ out, int n) {
  int lane = threadIdx.x & 63;
  int wid = threadIdx.x >> 6;
  float ta = tav[lane], tc = tcv[lane];
  int gw = blockIdx.x * 4 + wid, nw = gridDim.x * 4;
  for (int i = gw; i < n; i += nw) {
    float di = dinv[i];
    float acc = fmaxf(b2f(z16[(size_t)i * 64 + lane]) * ta + tc, 0.f) * di;
    float acc2 = 0.f;
    int st = offs[i], en = offs[i + 1];
    for (int base = st; base < en; base += 64) {
      int idx = base + lane;
      int v = (idx < en) ? csr[idx] : 0;
      int cnt = min(64, en - base);
      int j = 0;
      for (; j + 3 < cnt; j += 4) {
        int s0 = __builtin_amdgcn_readfirstlane(__shfl(v, j));
        int s1 = __builtin_amdgcn_readfirstlane(__shfl(v, j + 1));
        int s2 = __builtin_amdgcn_readfirstlane(__shfl(v, j + 2));
        int s3 = __builtin_amdgcn_readfirstlane(__shfl(v, j + 3));
        float z0 = b2f(z16[(size_t)s0 * 64 + lane]);
        float z1 = b2f(z16[(size_t)s1 * 64 + lane]);
        float z2 = b2f(z16[(size_t)s2 * 64 + lane]);
        float z3 = b2f(z16[(size_t)s3 * 64 + lane]);
        acc  += fmaxf(z0 * ta + tc, 0.f) * dinv[s0] + fmaxf(z1 * ta + tc, 0.f) * dinv[s1];
        acc2 += fmaxf(z2 * ta + tc, 0.f) * dinv[s2] + fmaxf(z3 * ta + tc, 0.f) * dinv[s3];
      }
      for (; j < cnt; ++j) {
        int s = __builtin_amdgcn_readfirstlane(__shfl(v, j));
        acc += fmaxf(b2f(z16[(size_t)s * 64 + lane]) * ta + tc, 0.f) * dinv[s];
      }
    }
    acc += acc2;
    if (SCALE) acc *= di;
    out[(size_t)i * 64 + lane] = acc;
  }
}

// ---------------- GEMM: z16 = bf16(dinv*(a@W) + bias), fused BN per-block partials ----

template <int K, int AS>
__global__ __launch_bounds__(256) void gemm_agg(const float* __restrict__ A, const float* __restrict__ W,
                                                const float* __restrict__ bias, const float* __restrict__ dinv,
                                                u16* __restrict__ z16, float* __restrict__ partial, int n) {
  __shared__ float Ws[K * 64];
  __shared__ float As[128 * (K + 1)];
  __shared__ float red[4][4][32];  // [wave][fs][16 sums | 16 sqs]
  int tid = threadIdx.x;
  int row0 = blockIdx.x * 128;
  for (int i = tid; i < K * 64; i += 256) Ws[i] = W[i];
  for (int i = tid; i < 128 * K; i += 256) {
    int r = i / K, k = i - r * K;
    int gr = row0 + r;
    As[r * (K + 1) + k] = (gr < n) ? A[(size_t)gr * AS + k] : 0.f;
  }
  __syncthreads();
  int rg = tid >> 2;
  int fs = tid & 3;
  float acc0[16], acc1[16];
#pragma unroll
  for (int j = 0; j < 16; ++j) { acc0[j] = 0.f; acc1[j] = 0.f; }
  const float* a0 = &As[(2 * rg) * (K + 1)];
  const float* a1 = &As[(2 * rg + 1) * (K + 1)];
  const float* wb = &Ws[fs * 16];
  for (int k = 0; k < K; ++k) {
    float x0 = a0[k], x1 = a1[k];
#pragma unroll
    for (int j = 0; j < 16; ++j) {
      float w = wb[k * 64 + j];
      acc0[j] += x0 * w;
      acc1[j] += x1 * w;
    }
  }
  int base = fs * 16;
  int r0 = row0 + 2 * rg;
  int r1 = r0 + 1;
  float dv0 = (r0 < n) ? dinv[r0] : 0.f;
  float dv1 = (r1 < n) ? dinv[r1] : 0.f;
  u32 pk0[8], pk1[8];
  u32 w0 = 0, w1 = 0;
#pragma unroll
  for (int j = 0; j < 16; ++j) {
    float t0 = acc0[j] * dv0 + bias[base + j];
    float t1 = acc1[j] * dv1 + bias[base + j];
    if (r0 >= n) t0 = 0.f;
    if (r1 >= n) t1 = 0.f;
    if ((j & 1) == 0) {
      w0 = f2b(t0);
      w1 = f2b(t1);
    } else {
      pk0[j >> 1] = w0 | ((u32)f2b(t0) << 16);
      pk1[j >> 1] = w1 | ((u32)f2b(t1) << 16);
    }
    acc0[j] = t0 + t1;           // per-thread BN sum (2 rows)
    acc1[j] = t0 * t0 + t1 * t1; // per-thread BN sumsq
  }
  if (r0 < n) {
    uint4* zp = (uint4*)&z16[(size_t)r0 * 64 + base];
    zp[0] = make_uint4(pk0[0], pk0[1], pk0[2], pk0[3]);
    zp[1] = make_uint4(pk0[4], pk0[5], pk0[6], pk0[7]);
  }
  if (r1 < n) {
    uint4* zp = (uint4*)&z16[(size_t)r1 * 64 + base];
    zp[0] = make_uint4(pk1[0], pk1[1], pk1[2], pk1[3]);
    zp[1] = make_uint4(pk1[4], pk1[5], pk1[6], pk1[7]);
  }
  // butterfly over the 16 lanes sharing this fs (lanes == fs mod 4)
#pragma unroll
  for (int j = 0; j < 16; ++j) {
    acc0[j] += __shfl_xor(acc0[j], 4);
    acc1[j] += __shfl_xor(acc1[j], 4);
    acc0[j] += __shfl_xor(acc0[j], 8);
    acc1[j] += __shfl_xor(acc1[j], 8);
    acc0[j] += __shfl_xor(acc0[j], 16);
    acc1[j] += __shfl_xor(acc1[j], 16);
    acc0[j] += __shfl_xor(acc0[j], 32);
    acc1[j] += __shfl_xor(acc1[j], 32);
  }
  int lane = tid & 63, wid = tid >> 6;
  if (lane < 4) {
#pragma unroll
    for (int j = 0; j < 16; ++j) {
      red[wid][lane][j] = acc0[j];
      red[wid][lane][16 + j] = acc1[j];
    }
  }
  __syncthreads();
  if (tid < 128) {
    int f = tid & 63;     // feature
    int half = tid >> 6;  // 0=sum, 1=sumsq
    int fsi = f >> 4, fj = (f & 15) + (half ? 16 : 0);
    float v = red[0][fsi][fj] + red[1][fsi][fj] + red[2][fsi][fj] + red[3][fsi][fj];
    partial[(size_t)blockIdx.x * 128 + half * 64 + f] = v;
  }
}

// ---------------- parallel BN finalize over nb per-block partials ----------------

__global__ __launch_bounds__(1024) void bn_final_kernel(const float* __restrict__ partial, int nb,
                                                        const float* __restrict__ g,
                                                        const float* __restrict__ bt,
                                                        float* __restrict__ a, float* __restrict__ c,
                                                        float n) {
  __shared__ float sh[16][128];
  int t = threadIdx.x;
  int grp = t >> 6, lane = t & 63;
  float s = 0.f, q = 0.f;
  for (int i = grp; i < nb; i += 16) {
    s += partial[(size_t)i * 128 + lane];
    q += partial[(size_t)i * 128 + 64 + lane];
  }
  sh[grp][lane] = s;
  sh[grp][64 + lane] = q;
  __syncthreads();
  for (int str = 8; str >= 1; str >>= 1) {
    if (grp < str) {
      sh[grp][lane] += sh[grp + str][lane];
      sh[grp][64 + lane] += sh[grp + str][64 + lane];
    }
    __syncthreads();
  }
  if (grp == 0) {
    float mu = sh[0][lane] / n;
    float var = fmaxf(sh[0][64 + lane] / n - mu * mu, 0.f);
    float rstd = rsqrtf(var + BN_EPS);
    float av = g[lane] * rstd;
    a[lane] = av;
    c[lane] = bt[lane] - mu * av;
  }
}

// ---------------- pool ----------------

__global__ __launch_bounds__(64) void pool_kernel(const float* __restrict__ v3,
                                                  const int* __restrict__ goffs,
                                                  float* __restrict__ ep, int B) {
  int b = blockIdx.x, t = threadIdx.x;
  int st = goffs[b], en = goffs[b + 1];
  float s = 0.f;
  int r = st;
  for (; r + 1 < en; r += 2) s += v3[(size_t)r * 64 + t] + v3[(size_t)(r + 1) * 64 + t];
  if (r < en) s += v3[(size_t)r * 64 + t];
  int c = en - st;
  ep[(size_t)b * 64 + t] = s / (float)max(c, 1);
}

// ---------------- heads ----------------

__global__ __launch_bounds__(256) void heads_kernel(
    const float* __restrict__ ep, const int* __restrict__ goffs,
    const float* __restrict__ W3, const float* __restrict__ b3,
    const float* __restrict__ Wo1, const float* __restrict__ bo1,
    const float* __restrict__ Wo2, const float* __restrict__ bo2,
    const float* __restrict__ Wp1, const float* __restrict__ bp1,
    const float* __restrict__ Wp2, const float* __restrict__ bp2,
    const float* __restrict__ Wp3, const float* __restrict__ bp3,
    const float* __restrict__ Wd1, const float* __restrict__ bd1,
    const float* __restrict__ Wd2, const float* __restrict__ bd2,
    float* __restrict__ out_op, float* __restrict__ out_p, float* __restrict__ out_d,
    float* __restrict__ enc_out, int B) {
  __shared__ float epl[16 * 64];
  __shared__ float es[16 * 128];
  __shared__ float t1[16 * 64];
  __shared__ float t2[16 * 64];
  int tid = threadIdx.x;
  int g0 = blockIdx.x * 16;
  for (int i = tid; i < 16 * 64; i += 256) epl[i] = ep[(size_t)g0 * 64 + i];
  __syncthreads();
  for (int o = tid; o < 16 * 128; o += 256) {
    int r = o >> 7, c = o & 127;
    float a = b3[c];
    for (int k = 0; k < 64; ++k) a += epl[r * 64 + k] * W3[k * 128 + c];
    if (goffs[g0 + r + 1] - goffs[g0 + r] == 0) a = 0.f;
    es[o] = a;
    enc_out[(size_t)(g0 + r) * 128 + c] = a;
  }
  __syncthreads();
  for (int o = tid; o < 16 * 64; o += 256) {
    int r = o >> 6, c = o & 63;
    float a = bo1[c];
    for (int k = 0; k < 128; k++) a += es[r * 128 + k] * Wo1[k * 64 + c];
    t1[o] = fmaxf(a, 0.f);
  }
  __syncthreads();
  for (int o = tid; o < 16 * 13; o += 256) {
    int r = o / 13, c = o - r * 13;
    float a = bo2[c];
    for (int k = 0; k < 64; k++) a += t1[r * 64 + k] * Wo2[k * 13 + c];
    out_op[(size_t)(g0 + r) * 13 + c] = a;
  }
  __syncthreads();
  for (int o = tid; o < 16 * 64; o += 256) {
    int r = o >> 6, c = o & 63;
    float a = bp1[c];
    for (int k = 0; k < 128; k++) a += es[r * 128 + k] * Wp1[k * 64 + c];
    t1[o] = fmaxf(a, 0.f);
  }
  __syncthreads();
  for (int o = tid; o < 16 * 64; o += 256) {
    int r = o >> 6, c = o & 63;
    float a = bp2[c];
    for (int k = 0; k < 64; k++) a += t1[r * 64 + k] * Wp2[k * 64 + c];
    t2[o] = fmaxf(a, 0.f);
  }
  __syncthreads();
  for (int o = tid; o < 16; o += 256) {
    float a = bp3[0];
    for (int k = 0; k < 64; k++) a += t2[o * 64 + k] * Wp3[k];
    out_p[g0 + o] = a;
  }
  __syncthreads();
  for (int o = tid; o < 16 * 64; o += 256) {
    int r = o >> 6, c = o & 63;
    float a = bd1[c];
    for (int k = 0; k < 128; k++) a += es[r * 128 + k] * Wd1[k * 64 + c];
    t1[o] = fmaxf(a, 0.f);
  }
  __syncthreads();
  for (int o = tid; o < 16 * 2; o += 256) {
    int r = o >> 1, c = o & 1;
    float a = bd2[c];
    for (int k = 0; k < 64; k++) a += t1[r * 64 + k] * Wd2[k * 2 + c];
    out_d[(size_t)(g0 + r) * 2 + c] = a;
  }
}

// ---------------- launch ----------------

extern "C" void kernel_launch(void* const* d_in, const int* in_sizes, int n_in,
                              void* d_out, int out_size, void* d_ws, size_t ws_size,
                              hipStream_t stream) {
  const float* x   = (const float*)d_in[0];
  const int*   ei  = (const int*)d_in[1];
  const int*   bat = (const int*)d_in[2];
  const float* W1 = (const float*)d_in[3];  const float* b1  = (const float*)d_in[4];
  const float* g1 = (const float*)d_in[5];  const float* bt1 = (const float*)d_in[6];
  const float* W2 = (const float*)d_in[7];  const float* b2  = (const float*)d_in[8];
  const float* g2 = (const float*)d_in[9];  const float* bt2 = (const float*)d_in[10];
  const float* W3 = (const float*)d_in[11]; const float* b3  = (const float*)d_in[12];
  const float* Wo1 = (const float*)d_in[13]; const float* bo1 = (const float*)d_in[14];
  const float* Wo2 = (const float*)d_in[15]; const float* bo2 = (const float*)d_in[16];
  const float* Wp1 = (const float*)d_in[17]; const float* bp1 = (const float*)d_in[18];
  const float* Wp2 = (const float*)d_in[19]; const float* bp2 = (const float*)d_in[20];
  const float* Wp3 = (const float*)d_in[21]; const float* bp3 = (const float*)d_in[22];
  const float* Wd1 = (const float*)d_in[23]; const float* bd1 = (const float*)d_in[24];
  const float* Wd2 = (const float*)d_in[25]; const float* bd2 = (const float*)d_in[26];

  int N = in_sizes[0] / 20;
  int E = in_sizes[1] / 2;
  int B = out_size / 144;  // 13 + 1 + 2 + 128
  const int* esrc = ei;
  const int* edst = ei + E;
  int NB = (N + (1 << BSH) - 1) >> BSH;

  char* ws = (char*)d_ws;
  size_t off = 0;
  auto alloc = [&](size_t bytes) -> char* {
    char* p = ws + off;
    off = (off + bytes + 255) & ~(size_t)255;
    return p;
  };
  int*   gcur  = (int*)alloc((size_t)NB * 4);
  int*   deg   = (int*)alloc((size_t)N * 4);
  float* dinv  = (float*)alloc((size_t)N * 4);
  int*   offs  = (int*)alloc(((size_t)N + 1) * 4);
  int*   bsum  = (int*)alloc(128 * 4);
  int*   goffs = (int*)alloc(((size_t)B + 1) * 4);
  float* bn    = (float*)alloc(512 * 4);
  float* partial = (float*)alloc((size_t)1024 * 128 * 4);
  unsigned long long* temp = (unsigned long long*)alloc((size_t)NB * CAP * 8);
  int*   csr   = (int*)alloc((size_t)E * 4);
  u16*   x16   = (u16*)alloc((size_t)N * 32 * 2);
  u16*   z16   = (u16*)alloc((size_t)N * 64 * 2);
  float* aggf  = (float*)alloc((size_t)N * 64 * 4);
  float* ep    = (float*)alloc((size_t)B * 64 * 4);

  float* ta1 = bn + 256, *tc1 = bn + 320;
  float* ta2 = bn + 384, *tc2 = bn + 448;

  float* out_op = (float*)d_out;
  float* out_p  = out_op + (size_t)B * 13;
  float* out_d  = out_p + B;
  float* enc    = out_d + (size_t)B * 2;

  hipLaunchKernelGGL(bound_kernel, dim3((N + 255) / 256), dim3(256), 0, stream,
                     bat, goffs, gcur, N, B, NB);
  hipLaunchKernelGGL(passA, dim3(256), dim3(256), 0, stream, edst, esrc, gcur, temp, E, NB);
  hipLaunchKernelGGL(passB1, dim3(NB), dim3(512), 0, stream, temp, gcur, deg, dinv, N);
  int nb1 = (N + 1023) / 1024;
  hipLaunchKernelGGL(scan_p1, dim3(nb1), dim3(1024), 0, stream, deg, offs, bsum, N);
  hipLaunchKernelGGL(scan_p2, dim3(1), dim3(128), 0, stream, bsum, nb1);
  hipLaunchKernelGGL(scan_p3, dim3(nb1), dim3(1024), 0, stream, offs, bsum, N, E);
  hipLaunchKernelGGL(passB2, dim3(NB), dim3(512), 0, stream, temp, gcur, offs, csr, N);

  int gblocks = (N + 127) / 128;
  // layer 1: prex -> gather -> gemm(20->64, fused BN partials) -> bn_final
  hipLaunchKernelGGL(prex_kernel, dim3(2048), dim3(256), 0, stream, x, dinv, x16, N);
  hipLaunchKernelGGL(agg32x_kernel, dim3(2048), dim3(256), 0, stream, x16, offs, csr, aggf, N);
  hipLaunchKernelGGL((gemm_agg<20, 32>), dim3(gblocks), dim3(256), 0, stream,
                     aggf, W1, b1, dinv, z16, partial, N);
  hipLaunchKernelGGL(bn_final_kernel, dim3(1), dim3(1024), 0, stream,
                     partial, gblocks, g1, bt1, ta1, tc1, (float)N);
  // layer 2
  hipLaunchKernelGGL((agg64t_kernel<false>), dim3(2048), dim3(256), 0, stream,
                     z16, ta1, tc1, offs, csr, dinv, aggf, N);
  hipLaunchKernelGGL((gemm_agg<64, 64>), dim3(gblocks), dim3(256), 0, stream,
                     aggf, W2, b2, dinv, z16, partial, N);
  hipLaunchKernelGGL(bn_final_kernel, dim3(1), dim3(1024), 0, stream,
                     partial, gblocks, g2, bt2, ta2, tc2, (float)N);
  // layer 3
  hipLaunchKernelGGL((agg64t_kernel<true>), dim3(2048), dim3(256), 0, stream,
                     z16, ta2, tc2, offs, csr, dinv, aggf, N);
  hipLaunchKernelGGL(pool_kernel, dim3(B), dim3(64), 0, stream, aggf, goffs, ep, B);
  hipLaunchKernelGGL(heads_kernel, dim3(B / 16), dim3(256), 0, stream, ep, goffs, W3, b3,
                     Wo1, bo1, Wo2, bo2, Wp1, bp1, Wp2, bp2, Wp3, bp3, Wd1, bd1, Wd2, bd2,
                     out_op, out_p, out_d, enc, B);
}